// Round 1
// baseline (2498.040 us; speedup 1.0000x reference)
//
#include <hip/hip_runtime.h>
#include <cmath>

#define B_ 4
#define S_ 2048
#define D_ 768
#define H_ 12
#define HD_ 64
#define SCALE_ 0.125f

// ---------------------------------------------------------------------------
// GEMM: out = (A[M,768] @ W[768,768] + bias[768]) * scale
// BM=BN=64, BK=16, 256 threads (16x16), 4x4 micro-tile per thread.
// SPLIT_HEADS: write to [B,H,S,HD] layout (for Q/K/V); else plain [M,768].
// ---------------------------------------------------------------------------
template<bool SPLIT_HEADS>
__global__ __launch_bounds__(256)
void gemm_bias(const float* __restrict__ A, const float* __restrict__ W,
               const float* __restrict__ bias, float* __restrict__ out,
               float scale)
{
    __shared__ float As_t[16 * 68];  // [k][m] (transposed A tile), pad 68
    __shared__ float Bs[16 * 68];    // [k][n], pad 68

    const int tid = threadIdx.x;
    const int tx = tid & 15;         // output col group
    const int ty = tid >> 4;         // output row group
    const int m0 = blockIdx.x * 64;
    const int n0 = blockIdx.y * 64;

    // loader indices
    const int arow = tid >> 2;              // 0..63
    const int ac4  = (tid & 3) << 2;        // 0,4,8,12
    const int brow = tid >> 4;              // 0..15
    const int bc4  = (tid & 15) << 2;       // 0..60

    float c[4][4] = {};

    for (int k0 = 0; k0 < 768; k0 += 16) {
        float4 av = *(const float4*)&A[(size_t)(m0 + arow) * 768 + k0 + ac4];
        float4 bv = *(const float4*)&W[(size_t)(k0 + brow) * 768 + n0 + bc4];
        __syncthreads();  // previous iteration's LDS reads complete
        As_t[(ac4 + 0) * 68 + arow] = av.x;
        As_t[(ac4 + 1) * 68 + arow] = av.y;
        As_t[(ac4 + 2) * 68 + arow] = av.z;
        As_t[(ac4 + 3) * 68 + arow] = av.w;
        *(float4*)&Bs[brow * 68 + bc4] = bv;
        __syncthreads();

        #pragma unroll
        for (int kk = 0; kk < 16; ++kk) {
            float4 a4 = *(float4*)&As_t[kk * 68 + ty * 4];
            float4 b4 = *(float4*)&Bs[kk * 68 + tx * 4];
            c[0][0] = fmaf(a4.x, b4.x, c[0][0]);
            c[0][1] = fmaf(a4.x, b4.y, c[0][1]);
            c[0][2] = fmaf(a4.x, b4.z, c[0][2]);
            c[0][3] = fmaf(a4.x, b4.w, c[0][3]);
            c[1][0] = fmaf(a4.y, b4.x, c[1][0]);
            c[1][1] = fmaf(a4.y, b4.y, c[1][1]);
            c[1][2] = fmaf(a4.y, b4.z, c[1][2]);
            c[1][3] = fmaf(a4.y, b4.w, c[1][3]);
            c[2][0] = fmaf(a4.z, b4.x, c[2][0]);
            c[2][1] = fmaf(a4.z, b4.y, c[2][1]);
            c[2][2] = fmaf(a4.z, b4.z, c[2][2]);
            c[2][3] = fmaf(a4.z, b4.w, c[2][3]);
            c[3][0] = fmaf(a4.w, b4.x, c[3][0]);
            c[3][1] = fmaf(a4.w, b4.y, c[3][1]);
            c[3][2] = fmaf(a4.w, b4.z, c[3][2]);
            c[3][3] = fmaf(a4.w, b4.w, c[3][3]);
        }
    }

    const int n_base = n0 + tx * 4;
    float4 bb = *(const float4*)&bias[n_base];
    #pragma unroll
    for (int i = 0; i < 4; ++i) {
        const int m = m0 + ty * 4 + i;
        float4 o;
        o.x = (c[i][0] + bb.x) * scale;
        o.y = (c[i][1] + bb.y) * scale;
        o.z = (c[i][2] + bb.z) * scale;
        o.w = (c[i][3] + bb.w) * scale;
        if (SPLIT_HEADS) {
            const int b = m >> 11;        // /S_
            const int s = m & 2047;       // %S_
            const int h = n0 >> 6;        // BN==HD, one head per block col
            const int hd = tx * 4;        // n_base & 63
            *(float4*)&out[(((size_t)b * H_ + h) * S_ + s) * HD_ + hd] = o;
        } else {
            *(float4*)&out[(size_t)m * 768 + n_base] = o;
        }
    }
}

// ---------------------------------------------------------------------------
// Flash attention: Q,K,V in [B,H,S,HD] fp32 (Q pre-scaled). mask[B,S] added
// over keys. Output written merged-head: [B,S,D].
// Block = 256 threads (4 waves), 32 query rows; KV tiles of 64.
// Lane l of wave w: local row r = w*8 + l/8, slot = l%8 (8 keys / 8 dims).
// ---------------------------------------------------------------------------
__global__ __launch_bounds__(256)
void attn_kernel(const float* __restrict__ Q, const float* __restrict__ K,
                 const float* __restrict__ V, const float* __restrict__ mask,
                 float* __restrict__ out)
{
    __shared__ float Qs[32 * 68];
    __shared__ float Ks[64 * 68];
    __shared__ float Vs[64 * 68];
    __shared__ float Ps[32 * 65];

    const int tid  = threadIdx.x;
    const int lane = tid & 63;
    const int wave = tid >> 6;
    const int r    = wave * 8 + (lane >> 3);  // local q row 0..31
    const int slot = lane & 7;                // 0..7
    const int q0   = blockIdx.x * 32;
    const int h    = blockIdx.y;
    const int b    = blockIdx.z;

    const size_t bh = (size_t)b * H_ + h;
    const float* Qg = Q + (bh * S_ + q0) * HD_;
    const float* Kg = K + bh * S_ * HD_;
    const float* Vg = V + bh * S_ * HD_;
    const float* mg = mask + (size_t)b * S_;

    // stage Q tile (32x64)
    for (int f = tid; f < 512; f += 256) {
        const int row = f >> 4, c4 = (f & 15) << 2;
        *(float4*)&Qs[row * 68 + c4] = *(const float4*)&Qg[row * 64 + c4];
    }

    float acc[8] = {};
    float m_old = -INFINITY;
    float l_sum = 0.f;

    for (int kt = 0; kt < S_ / 64; ++kt) {
        const int k0 = kt * 64;
        __syncthreads();  // previous iter's Vs/Ks reads done (and Q staged, 1st iter)
        for (int f = tid; f < 1024; f += 256) {
            const int row = f >> 4, c4 = (f & 15) << 2;
            *(float4*)&Ks[row * 68 + c4] = *(const float4*)&Kg[(k0 + row) * 64 + c4];
        }
        for (int f = tid; f < 1024; f += 256) {
            const int row = f >> 4, c4 = (f & 15) << 2;
            *(float4*)&Vs[row * 68 + c4] = *(const float4*)&Vg[(k0 + row) * 64 + c4];
        }
        __syncthreads();

        // scores: row r, keys slot*8 .. slot*8+7
        float s[8];
        #pragma unroll
        for (int kk = 0; kk < 8; ++kk) s[kk] = 0.f;
        #pragma unroll
        for (int d4 = 0; d4 < 16; ++d4) {
            float4 q4 = *(float4*)&Qs[r * 68 + d4 * 4];
            #pragma unroll
            for (int kk = 0; kk < 8; ++kk) {
                float4 k4 = *(float4*)&Ks[(slot * 8 + kk) * 68 + d4 * 4];
                s[kk] = fmaf(q4.x, k4.x, s[kk]);
                s[kk] = fmaf(q4.y, k4.y, s[kk]);
                s[kk] = fmaf(q4.z, k4.z, s[kk]);
                s[kk] = fmaf(q4.w, k4.w, s[kk]);
            }
        }
        #pragma unroll
        for (int kk = 0; kk < 8; ++kk) s[kk] += mg[k0 + slot * 8 + kk];

        // online softmax (8-lane group reduce; lanes of a group share row r)
        float tmax = s[0];
        #pragma unroll
        for (int kk = 1; kk < 8; ++kk) tmax = fmaxf(tmax, s[kk]);
        tmax = fmaxf(tmax, __shfl_xor(tmax, 1));
        tmax = fmaxf(tmax, __shfl_xor(tmax, 2));
        tmax = fmaxf(tmax, __shfl_xor(tmax, 4));

        const float m_new = fmaxf(m_old, tmax);
        const float fac = __expf(m_old - m_new);  // first iter: exp(-inf)=0
        float psum = 0.f;
        #pragma unroll
        for (int kk = 0; kk < 8; ++kk) {
            const float p = __expf(s[kk] - m_new);
            psum += p;
            Ps[r * 65 + slot * 8 + kk] = p;
        }
        psum += __shfl_xor(psum, 1);
        psum += __shfl_xor(psum, 2);
        psum += __shfl_xor(psum, 4);
        l_sum = l_sum * fac + psum;
        m_old = m_new;
        #pragma unroll
        for (int j = 0; j < 8; ++j) acc[j] *= fac;

        // PV: row r, dims slot*8 .. slot*8+7  (Ps written by own wave only —
        // per-wave in-order DS pipe makes the RAW safe without a barrier)
        #pragma unroll 8
        for (int k = 0; k < 64; ++k) {
            const float p = Ps[r * 65 + k];
            float4 v0 = *(float4*)&Vs[k * 68 + slot * 8];
            float4 v1 = *(float4*)&Vs[k * 68 + slot * 8 + 4];
            acc[0] = fmaf(p, v0.x, acc[0]);
            acc[1] = fmaf(p, v0.y, acc[1]);
            acc[2] = fmaf(p, v0.z, acc[2]);
            acc[3] = fmaf(p, v0.w, acc[3]);
            acc[4] = fmaf(p, v1.x, acc[4]);
            acc[5] = fmaf(p, v1.y, acc[5]);
            acc[6] = fmaf(p, v1.z, acc[6]);
            acc[7] = fmaf(p, v1.w, acc[7]);
        }
    }

    const float inv = 1.f / l_sum;
    float* dst = out + ((size_t)b * S_ + q0 + r) * D_ + h * HD_ + slot * 8;
    float4 o0 = {acc[0] * inv, acc[1] * inv, acc[2] * inv, acc[3] * inv};
    float4 o1 = {acc[4] * inv, acc[5] * inv, acc[6] * inv, acc[7] * inv};
    *(float4*)dst = o0;
    *(float4*)(dst + 4) = o1;
}

// ---------------------------------------------------------------------------
extern "C" void kernel_launch(void* const* d_in, const int* in_sizes, int n_in,
                              void* d_out, int out_size, void* d_ws, size_t ws_size,
                              hipStream_t stream)
{
    const float* x    = (const float*)d_in[0];
    const float* mask = (const float*)d_in[1];
    const float* Wq   = (const float*)d_in[2];
    const float* bq   = (const float*)d_in[3];
    const float* Wk   = (const float*)d_in[4];
    const float* bk   = (const float*)d_in[5];
    const float* Wv   = (const float*)d_in[6];
    const float* bv   = (const float*)d_in[7];
    const float* Wo   = (const float*)d_in[8];
    const float* bo   = (const float*)d_in[9];
    float* out = (float*)d_out;

    float* ws = (float*)d_ws;
    const size_t NE = (size_t)B_ * S_ * D_;  // 6291456
    float* qb = ws;
    float* kb = ws + NE;
    float* vb = ws + 2 * NE;
    float* ab = ws + 3 * NE;

    dim3 gg(8192 / 64, 768 / 64);
    gemm_bias<true><<<gg, 256, 0, stream>>>(x, Wq, bq, qb, SCALE_);
    gemm_bias<true><<<gg, 256, 0, stream>>>(x, Wk, bk, kb, 1.0f);
    gemm_bias<true><<<gg, 256, 0, stream>>>(x, Wv, bv, vb, 1.0f);

    dim3 ga(S_ / 32, H_, B_);
    attn_kernel<<<ga, 256, 0, stream>>>(qb, kb, vb, mask, ab);

    gemm_bias<false><<<gg, 256, 0, stream>>>(ab, Wo, bo, out, 1.0f);
}

// Round 2
// 716.355 us; speedup vs baseline: 3.4872x; 3.4872x over previous
//
#include <hip/hip_runtime.h>
#include <cmath>

#define B_ 4
#define S_ 2048
#define D_ 768
#define H_ 12
#define HD_ 64
#define SCALE_ 0.125f

typedef unsigned short ushortT;
typedef __attribute__((ext_vector_type(8))) __bf16 bf16x8;
typedef __attribute__((ext_vector_type(4))) float f32x4;

__device__ inline ushortT f2bf(float f) {
    return __builtin_bit_cast(ushortT, (__bf16)f);
}

// ---------------------------------------------------------------------------
// GEMM: out = (A[M,768] @ W[768,768] + bias[768]) * scale
// BM=BN=64, BK=16, 256 threads (16x16), 4x4 micro-tile, fp32 VALU compute.
// BF16OUT: write bf16 split-head layout [B,H,S,HD]; else fp32 flat [M,768].
// ---------------------------------------------------------------------------
template<bool BF16OUT>
__global__ __launch_bounds__(256)
void gemm_bias(const float* __restrict__ A, const float* __restrict__ W,
               const float* __restrict__ bias, void* __restrict__ outv,
               float scale)
{
    __shared__ float As_t[16 * 68];  // [k][m] transposed A tile
    __shared__ float Bs[16 * 68];    // [k][n]

    const int tid = threadIdx.x;
    const int tx = tid & 15;
    const int ty = tid >> 4;
    const int m0 = blockIdx.x * 64;
    const int n0 = blockIdx.y * 64;

    const int arow = tid >> 2;
    const int ac4  = (tid & 3) << 2;
    const int brow = tid >> 4;
    const int bc4  = (tid & 15) << 2;

    float c[4][4] = {};

    for (int k0 = 0; k0 < 768; k0 += 16) {
        float4 av = *(const float4*)&A[(size_t)(m0 + arow) * 768 + k0 + ac4];
        float4 bv = *(const float4*)&W[(size_t)(k0 + brow) * 768 + n0 + bc4];
        __syncthreads();
        As_t[(ac4 + 0) * 68 + arow] = av.x;
        As_t[(ac4 + 1) * 68 + arow] = av.y;
        As_t[(ac4 + 2) * 68 + arow] = av.z;
        As_t[(ac4 + 3) * 68 + arow] = av.w;
        *(float4*)&Bs[brow * 68 + bc4] = bv;
        __syncthreads();

        #pragma unroll
        for (int kk = 0; kk < 16; ++kk) {
            float4 a4 = *(float4*)&As_t[kk * 68 + ty * 4];
            float4 b4 = *(float4*)&Bs[kk * 68 + tx * 4];
            c[0][0] = fmaf(a4.x, b4.x, c[0][0]);
            c[0][1] = fmaf(a4.x, b4.y, c[0][1]);
            c[0][2] = fmaf(a4.x, b4.z, c[0][2]);
            c[0][3] = fmaf(a4.x, b4.w, c[0][3]);
            c[1][0] = fmaf(a4.y, b4.x, c[1][0]);
            c[1][1] = fmaf(a4.y, b4.y, c[1][1]);
            c[1][2] = fmaf(a4.y, b4.z, c[1][2]);
            c[1][3] = fmaf(a4.y, b4.w, c[1][3]);
            c[2][0] = fmaf(a4.z, b4.x, c[2][0]);
            c[2][1] = fmaf(a4.z, b4.y, c[2][1]);
            c[2][2] = fmaf(a4.z, b4.z, c[2][2]);
            c[2][3] = fmaf(a4.z, b4.w, c[2][3]);
            c[3][0] = fmaf(a4.w, b4.x, c[3][0]);
            c[3][1] = fmaf(a4.w, b4.y, c[3][1]);
            c[3][2] = fmaf(a4.w, b4.z, c[3][2]);
            c[3][3] = fmaf(a4.w, b4.w, c[3][3]);
        }
    }

    const int n_base = n0 + tx * 4;
    float4 bb = *(const float4*)&bias[n_base];
    #pragma unroll
    for (int i = 0; i < 4; ++i) {
        const int m = m0 + ty * 4 + i;
        float o0 = (c[i][0] + bb.x) * scale;
        float o1 = (c[i][1] + bb.y) * scale;
        float o2 = (c[i][2] + bb.z) * scale;
        float o3 = (c[i][3] + bb.w) * scale;
        if (BF16OUT) {
            // split heads: [B,H,S,HD] bf16
            const int b = m >> 11;
            const int s = m & 2047;
            const int h = n0 >> 6;     // BN==HD
            const int hd = tx * 4;
            ushort4 ob;
            ob.x = f2bf(o0); ob.y = f2bf(o1); ob.z = f2bf(o2); ob.w = f2bf(o3);
            ushortT* outb = (ushortT*)outv;
            *(ushort4*)&outb[(((size_t)b * H_ + h) * S_ + s) * HD_ + hd] = ob;
        } else {
            float4 o = {o0, o1, o2, o3};
            *(float4*)&((float*)outv)[(size_t)m * 768 + n_base] = o;
        }
    }
}

// ---------------------------------------------------------------------------
// Transpose V [B,H,S,HD] bf16 -> Vt [B,H,HD,S] bf16. Tile 64x64 per block.
// ---------------------------------------------------------------------------
__global__ __launch_bounds__(256)
void transpose_v(const ushortT* __restrict__ V, ushortT* __restrict__ Vt)
{
    __shared__ __align__(16) ushortT T[64 * 68];
    const int tid = threadIdx.x;
    const size_t bh = (size_t)blockIdx.z * H_ + blockIdx.y;
    const int s0 = blockIdx.x * 64;

    for (int t2 = tid; t2 < 512; t2 += 256) {
        const int row = t2 >> 3, c = t2 & 7;
        *(float4*)&T[row * 68 + c * 8] =
            *(const float4*)&V[(bh * S_ + s0 + row) * HD_ + c * 8];
    }
    __syncthreads();
    for (int t2 = tid; t2 < 512; t2 += 256) {
        const int hd = t2 >> 3, c = t2 & 7;
        union { ushortT u[8]; float4 f; } tmp;
        #pragma unroll
        for (int i = 0; i < 8; ++i) tmp.u[i] = T[(c * 8 + i) * 68 + hd];
        *(float4*)&Vt[(bh * HD_ + hd) * S_ + s0 + c * 8] = tmp.f;
    }
}

// ---------------------------------------------------------------------------
// Flash attention, bf16 MFMA (16x16x32). Q pre-scaled bf16 [B,H,S,HD];
// K bf16 [B,H,S,HD]; Vt bf16 [B,H,HD,S]; mask f32 [B,S]; out f32 [B,S,D].
// Block = 256 thr = 4 waves; 64 Q rows/block (16/wave); KV tiles of 64.
// LDS K/V tiles: row-major 64x64 bf16 with 16B-chunk XOR swizzle (c ^= row&7).
// ---------------------------------------------------------------------------
__global__ __launch_bounds__(256)
void attn_mfma(const ushortT* __restrict__ Q, const ushortT* __restrict__ K,
               const ushortT* __restrict__ Vt, const float* __restrict__ mask,
               float* __restrict__ out)
{
    __shared__ __align__(16) ushortT Ks[64 * 64];      // 8 KB, swizzled
    __shared__ __align__(16) ushortT Vs[64 * 64];      // 8 KB, swizzled (Vt tile)
    __shared__ __align__(16) ushortT Ps[4][16 * 88];   // per-wave P, stride 88
    __shared__ float Ms[S_];                            // mask row, 8 KB

    const int tid  = threadIdx.x;
    const int lane = tid & 63;
    const int wave = tid >> 6;
    const int lr   = lane & 15;   // A-row / B-col / D-col selector
    const int lg   = lane >> 4;   // k-group 0..3
    const int q0   = blockIdx.x * 64;
    const int h    = blockIdx.y;
    const int b    = blockIdx.z;
    const size_t bh = (size_t)b * H_ + h;

    // stage mask row
    for (int f = tid; f < 512; f += 256)
        *(float4*)&Ms[f * 4] = *(const float4*)&mask[(size_t)b * S_ + f * 4];

    // Q A-fragments (held in registers for whole kernel)
    const ushortT* Qg = Q + (bh * S_ + q0 + wave * 16 + lr) * HD_;
    bf16x8 qf[2];
    qf[0] = __builtin_bit_cast(bf16x8, *(const float4*)(Qg + lg * 8));
    qf[1] = __builtin_bit_cast(bf16x8, *(const float4*)(Qg + 32 + lg * 8));

    const ushortT* Kg = K  + bh * S_ * HD_;
    const ushortT* Vg = Vt + bh * HD_ * S_;

    f32x4 acc[4];
    float mrun[4], lrun[4];
    #pragma unroll
    for (int j = 0; j < 4; ++j) {
        acc[j] = (f32x4){0.f, 0.f, 0.f, 0.f};
        mrun[j] = -INFINITY;
        lrun[j] = 0.f;
    }

    for (int kt = 0; kt < S_ / 64; ++kt) {
        const int k0 = kt * 64;
        __syncthreads();  // previous tile's LDS reads done (also covers mask stage)
        // stage K tile and Vt tile, 16B chunks with XOR swizzle
        #pragma unroll
        for (int t2 = tid; t2 < 512; t2 += 256) {
            const int row = t2 >> 3, c = t2 & 7, p = c ^ (row & 7);
            *(float4*)((char*)Ks + row * 128 + p * 16) =
                *(const float4*)(Kg + (size_t)(k0 + row) * HD_ + c * 8);
            *(float4*)((char*)Vs + row * 128 + p * 16) =
                *(const float4*)(Vg + (size_t)row * S_ + k0 + c * 8);
        }
        __syncthreads();

        // ---- QK^T: S_tile[16 q x 64 keys] per wave ----
        f32x4 s[4];
        #pragma unroll
        for (int cb = 0; cb < 4; ++cb) {
            s[cb] = (f32x4){0.f, 0.f, 0.f, 0.f};
            #pragma unroll
            for (int ks = 0; ks < 2; ++ks) {
                const int rk = cb * 16 + lr;            // key row in tile
                const int pp = (ks * 4 + lg) ^ (rk & 7);
                bf16x8 kf = __builtin_bit_cast(bf16x8,
                    *(const float4*)((const char*)Ks + rk * 128 + pp * 16));
                s[cb] = __builtin_amdgcn_mfma_f32_16x16x32_bf16(qf[ks], kf, s[cb], 0, 0, 0);
            }
        }

        // ---- mask + online softmax (rows = lg*4+j, cols = keys = lr) ----
        #pragma unroll
        for (int cb = 0; cb < 4; ++cb) {
            const float mv = Ms[k0 + cb * 16 + lr];
            #pragma unroll
            for (int j = 0; j < 4; ++j) s[cb][j] += mv;
        }
        float fac[4];
        #pragma unroll
        for (int j = 0; j < 4; ++j) {
            float t = fmaxf(fmaxf(s[0][j], s[1][j]), fmaxf(s[2][j], s[3][j]));
            t = fmaxf(t, __shfl_xor(t, 1));
            t = fmaxf(t, __shfl_xor(t, 2));
            t = fmaxf(t, __shfl_xor(t, 4));
            t = fmaxf(t, __shfl_xor(t, 8));
            const float mn = fmaxf(mrun[j], t);
            fac[j] = __expf(mrun[j] - mn);   // first iter: exp(-inf) = 0
            mrun[j] = mn;
        }
        float psum[4] = {0.f, 0.f, 0.f, 0.f};
        #pragma unroll
        for (int cb = 0; cb < 4; ++cb) {
            #pragma unroll
            for (int j = 0; j < 4; ++j) {
                const float p = __expf(s[cb][j] - mrun[j]);
                s[cb][j] = p;
                psum[j] += p;
            }
        }
        #pragma unroll
        for (int j = 0; j < 4; ++j) {
            float ps = psum[j];
            ps += __shfl_xor(ps, 1);
            ps += __shfl_xor(ps, 2);
            ps += __shfl_xor(ps, 4);
            ps += __shfl_xor(ps, 8);
            lrun[j] = lrun[j] * fac[j] + ps;
        }
        #pragma unroll
        for (int cb = 0; cb < 4; ++cb)
            #pragma unroll
            for (int j = 0; j < 4; ++j) acc[cb][j] *= fac[j];

        // ---- write P (bf16) to per-wave LDS: P[row=lg*4+j][col=cb*16+lr] ----
        #pragma unroll
        for (int cb = 0; cb < 4; ++cb) {
            #pragma unroll
            for (int j = 0; j < 4; ++j)
                Ps[wave][(lg * 4 + j) * 88 + cb * 16 + lr] = f2bf(s[cb][j]);
        }

        // ---- PV: O[16 q x 64 hd] += P[16 x 64] * V[64 keys x 64 hd] ----
        #pragma unroll
        for (int ks2 = 0; ks2 < 2; ++ks2) {
            bf16x8 pf = __builtin_bit_cast(bf16x8,
                *(const float4*)((const char*)&Ps[wave][0] + lr * 176 + (ks2 * 4 + lg) * 16));
            #pragma unroll
            for (int cb = 0; cb < 4; ++cb) {
                const int rv = cb * 16 + lr;            // hd row in Vt tile
                const int pp = (ks2 * 4 + lg) ^ (rv & 7);
                bf16x8 vf = __builtin_bit_cast(bf16x8,
                    *(const float4*)((const char*)Vs + rv * 128 + pp * 16));
                acc[cb] = __builtin_amdgcn_mfma_f32_16x16x32_bf16(pf, vf, acc[cb], 0, 0, 0);
            }
        }
    }

    // ---- epilogue: rows lg*4+j, col hd = cb*16+lr ----
    float inv[4];
    #pragma unroll
    for (int j = 0; j < 4; ++j) inv[j] = 1.f / lrun[j];
    #pragma unroll
    for (int cb = 0; cb < 4; ++cb) {
        #pragma unroll
        for (int j = 0; j < 4; ++j) {
            const size_t row = (size_t)b * S_ + q0 + wave * 16 + lg * 4 + j;
            out[row * D_ + h * HD_ + cb * 16 + lr] = acc[cb][j] * inv[j];
        }
    }
}

// ---------------------------------------------------------------------------
extern "C" void kernel_launch(void* const* d_in, const int* in_sizes, int n_in,
                              void* d_out, int out_size, void* d_ws, size_t ws_size,
                              hipStream_t stream)
{
    const float* x    = (const float*)d_in[0];
    const float* mask = (const float*)d_in[1];
    const float* Wq   = (const float*)d_in[2];
    const float* bq   = (const float*)d_in[3];
    const float* Wk   = (const float*)d_in[4];
    const float* bk   = (const float*)d_in[5];
    const float* Wv   = (const float*)d_in[6];
    const float* bv   = (const float*)d_in[7];
    const float* Wo   = (const float*)d_in[8];
    const float* bo   = (const float*)d_in[9];
    float* out = (float*)d_out;

    const size_t NE = (size_t)B_ * S_ * D_;  // 6291456
    ushortT* qb  = (ushortT*)d_ws;
    ushortT* kb  = qb + NE;
    ushortT* vb  = qb + 2 * NE;
    ushortT* vtb = qb + 3 * NE;
    float*   ab  = (float*)(qb + 4 * NE);

    dim3 gg(8192 / 64, 768 / 64);
    gemm_bias<true><<<gg, 256, 0, stream>>>(x, Wq, bq, qb, SCALE_);
    gemm_bias<true><<<gg, 256, 0, stream>>>(x, Wk, bk, kb, 1.0f);
    gemm_bias<true><<<gg, 256, 0, stream>>>(x, Wv, bv, vb, 1.0f);

    dim3 gt(S_ / 64, H_, B_);
    transpose_v<<<gt, 256, 0, stream>>>(vb, vtb);

    dim3 ga(S_ / 64, H_, B_);
    attn_mfma<<<ga, 256, 0, stream>>>(qb, kb, vtb, mask, ab);

    gemm_bias<false><<<gg, 256, 0, stream>>>(ab, Wo, bo, out, 1.0f);
}

// Round 3
// 245.564 us; speedup vs baseline: 10.1727x; 2.9172x over previous
//
#include <hip/hip_runtime.h>
#include <cmath>

#define B_ 4
#define S_ 2048
#define D_ 768
#define H_ 12
#define HD_ 64
#define SCALE_ 0.125f
#define M_ 8192

typedef unsigned short ushortT;
typedef __attribute__((ext_vector_type(8))) __bf16 bf16x8;
typedef __attribute__((ext_vector_type(4))) float f32x4;

typedef __attribute__((address_space(1))) const void glb_cv;
typedef __attribute__((address_space(3))) void lds_v;

__device__ inline ushortT f2bf(float f) {
    return __builtin_bit_cast(ushortT, (__bf16)f);
}

__device__ inline void gload_lds16(const void* g, void* l) {
    __builtin_amdgcn_global_load_lds((glb_cv*)g, (lds_v*)l, 16, 0, 0);
}

// ---------------------------------------------------------------------------
// convert x fp32 -> bf16, 8 el/thread
// ---------------------------------------------------------------------------
__global__ __launch_bounds__(256)
void convert_f32_bf16(const float* __restrict__ in, ushortT* __restrict__ out)
{
    const size_t i = ((size_t)blockIdx.x * 256 + threadIdx.x) * 8;
    float4 a = *(const float4*)(in + i);
    float4 b = *(const float4*)(in + i + 4);
    union { ushortT u[8]; float4 f; } o;
    o.u[0] = f2bf(a.x); o.u[1] = f2bf(a.y); o.u[2] = f2bf(a.z); o.u[3] = f2bf(a.w);
    o.u[4] = f2bf(b.x); o.u[5] = f2bf(b.y); o.u[6] = f2bf(b.z); o.u[7] = f2bf(b.w);
    *(float4*)(out + i) = o.f;
}

// ---------------------------------------------------------------------------
// transpose+convert W [768,768] f32 -> Wt [768,768] bf16 (Wt[n][k] = W[k][n]).
// z selects one of 4 weight matrices. 64x64 tiles.
// ---------------------------------------------------------------------------
__global__ __launch_bounds__(256)
void transpose_w(const float* __restrict__ W0, const float* __restrict__ W1,
                 const float* __restrict__ W2, const float* __restrict__ W3,
                 ushortT* __restrict__ wt4)
{
    const float* W = (blockIdx.z == 0) ? W0 : (blockIdx.z == 1) ? W1
                   : (blockIdx.z == 2) ? W2 : W3;
    ushortT* o = wt4 + (size_t)blockIdx.z * 768 * 768;
    __shared__ float T[64][65];
    const int tid = threadIdx.x;
    const int k0 = blockIdx.x * 64, n0 = blockIdx.y * 64;

    for (int t = tid; t < 1024; t += 256) {
        const int r = t >> 4, c4 = (t & 15) << 2;
        float4 v = *(const float4*)&W[(size_t)(k0 + r) * 768 + n0 + c4];
        T[r][c4 + 0] = v.x; T[r][c4 + 1] = v.y;
        T[r][c4 + 2] = v.z; T[r][c4 + 3] = v.w;
    }
    __syncthreads();
    for (int t = tid; t < 1024; t += 256) {
        const int r = t >> 4, c4 = (t & 15) << 2;
        union { ushortT u[4]; unsigned long long v; } ov;
        ov.u[0] = f2bf(T[c4 + 0][r]); ov.u[1] = f2bf(T[c4 + 1][r]);
        ov.u[2] = f2bf(T[c4 + 2][r]); ov.u[3] = f2bf(T[c4 + 3][r]);
        *(unsigned long long*)&o[(size_t)(n0 + r) * 768 + k0 + c4] = ov.v;
    }
}

// ---------------------------------------------------------------------------
// MFMA GEMM core: C[128x64] = A[m0..,768] * Bt[n0..,768]^T  (bf16, fp32 acc)
// BK=64; 4 waves in 2x2; per wave 64x32 (acc[4][2] of 16x16 fragments).
// LDS: linear dest via global_load_lds, source pre-swizzled (c ^= row&7 on
// 16B chunks), ds_read_b128 with the same swizzle.
// ---------------------------------------------------------------------------
__device__ inline void gemm_core_128x64(
    const ushortT* __restrict__ A, const ushortT* __restrict__ Bt,
    ushortT* As, ushortT* Bs, int m0, int n0, f32x4 acc[4][2])
{
    const int tid  = threadIdx.x;
    const int lane = tid & 63;
    const int wave = tid >> 6;
    const int lr = lane & 15, lg = lane >> 4;
    const int wr = wave >> 1, wc = wave & 1;

    #pragma unroll
    for (int mi = 0; mi < 4; ++mi)
        #pragma unroll
        for (int ni = 0; ni < 2; ++ni)
            acc[mi][ni] = (f32x4){0.f, 0.f, 0.f, 0.f};

    #pragma unroll 1
    for (int k0 = 0; k0 < 768; k0 += 64) {
        __syncthreads();   // prior LDS reads done
        #pragma unroll
        for (int it = 0; it < 4; ++it) {           // A tile: 1024 16B chunks
            const int ci = it * 256 + tid;
            const int row = ci >> 3, c = ci & 7;
            const int sc = c ^ (row & 7);
            gload_lds16(A + (size_t)(m0 + row) * 768 + k0 + sc * 8,
                        As + (size_t)(it * 256 + wave * 64) * 8);
        }
        #pragma unroll
        for (int it = 0; it < 2; ++it) {           // B tile: 512 16B chunks
            const int ci = it * 256 + tid;
            const int row = ci >> 3, c = ci & 7;
            const int sc = c ^ (row & 7);
            gload_lds16(Bt + (size_t)(n0 + row) * 768 + k0 + sc * 8,
                        Bs + (size_t)(it * 256 + wave * 64) * 8);
        }
        __syncthreads();   // compiler drains vmcnt before barrier

        #pragma unroll
        for (int ks = 0; ks < 2; ++ks) {
            bf16x8 af[4], bfr[2];
            #pragma unroll
            for (int mi = 0; mi < 4; ++mi) {
                const int row = wr * 64 + mi * 16 + lr;
                const int ch = (ks * 4 + lg) ^ (row & 7);
                af[mi] = __builtin_bit_cast(bf16x8, *(const float4*)(As + row * 64 + ch * 8));
            }
            #pragma unroll
            for (int ni = 0; ni < 2; ++ni) {
                const int row = wc * 32 + ni * 16 + lr;
                const int ch = (ks * 4 + lg) ^ (row & 7);
                bfr[ni] = __builtin_bit_cast(bf16x8, *(const float4*)(Bs + row * 64 + ch * 8));
            }
            #pragma unroll
            for (int mi = 0; mi < 4; ++mi)
                #pragma unroll
                for (int ni = 0; ni < 2; ++ni)
                    acc[mi][ni] = __builtin_amdgcn_mfma_f32_16x16x32_bf16(
                        af[mi], bfr[ni], acc[mi][ni], 0, 0, 0);
        }
    }
}

// ---------------------------------------------------------------------------
// QKV fused GEMM: z selects {Wq,Wk,Wv}; writes bf16 split-head [B,H,S,HD].
// ---------------------------------------------------------------------------
__global__ __launch_bounds__(256)
void qkv_gemm(const ushortT* __restrict__ xb, const ushortT* __restrict__ wt4,
              const float* __restrict__ bq, const float* __restrict__ bk,
              const float* __restrict__ bv,
              ushortT* __restrict__ qb, ushortT* __restrict__ kb,
              ushortT* __restrict__ vb)
{
    __shared__ __align__(16) ushortT As[128 * 64];
    __shared__ __align__(16) ushortT Bs[64 * 64];
    const int z = blockIdx.z;
    const ushortT* Wt = wt4 + (size_t)z * 768 * 768;
    const float* bias = (z == 0) ? bq : (z == 1) ? bk : bv;
    ushortT* out = (z == 0) ? qb : (z == 1) ? kb : vb;
    const float scale = (z == 0) ? SCALE_ : 1.0f;

    const int m0 = blockIdx.x * 128, n0 = blockIdx.y * 64;
    f32x4 acc[4][2];
    gemm_core_128x64(xb, Wt, As, Bs, m0, n0, acc);

    const int tid = threadIdx.x;
    const int lane = tid & 63, wave = tid >> 6;
    const int lr = lane & 15, lg = lane >> 4;
    const int wr = wave >> 1, wc = wave & 1;
    const int h = n0 >> 6;

    #pragma unroll
    for (int ni = 0; ni < 2; ++ni) {
        const int nn = wc * 32 + ni * 16 + lr;   // hd 0..63
        const float bb = bias[n0 + nn];
        #pragma unroll
        for (int mi = 0; mi < 4; ++mi) {
            #pragma unroll
            for (int j = 0; j < 4; ++j) {
                const int m = m0 + wr * 64 + mi * 16 + lg * 4 + j;
                const int b = m >> 11, s = m & 2047;
                out[(((size_t)b * H_ + h) * S_ + s) * HD_ + nn] =
                    f2bf((acc[mi][ni][j] + bb) * scale);
            }
        }
    }
}

// ---------------------------------------------------------------------------
// Output projection: ab bf16 [M,768] x Wo^T -> fp32 [M,768] + bias.
// ---------------------------------------------------------------------------
__global__ __launch_bounds__(256)
void o_gemm(const ushortT* __restrict__ ab, const ushortT* __restrict__ wto,
            const float* __restrict__ bo, float* __restrict__ out)
{
    __shared__ __align__(16) ushortT As[128 * 64];
    __shared__ __align__(16) ushortT Bs[64 * 64];
    const int m0 = blockIdx.x * 128, n0 = blockIdx.y * 64;
    f32x4 acc[4][2];
    gemm_core_128x64(ab, wto, As, Bs, m0, n0, acc);

    const int tid = threadIdx.x;
    const int lane = tid & 63, wave = tid >> 6;
    const int lr = lane & 15, lg = lane >> 4;
    const int wr = wave >> 1, wc = wave & 1;

    #pragma unroll
    for (int ni = 0; ni < 2; ++ni) {
        const int n = n0 + wc * 32 + ni * 16 + lr;
        const float bb = bo[n];
        #pragma unroll
        for (int mi = 0; mi < 4; ++mi) {
            #pragma unroll
            for (int j = 0; j < 4; ++j) {
                const int m = m0 + wr * 64 + mi * 16 + lg * 4 + j;
                out[(size_t)m * 768 + n] = acc[mi][ni][j] + bb;
            }
        }
    }
}

// ---------------------------------------------------------------------------
// Transpose V [B,H,S,HD] bf16 -> Vt [B,H,HD,S] bf16. Tile 64x64 per block.
// ---------------------------------------------------------------------------
__global__ __launch_bounds__(256)
void transpose_v(const ushortT* __restrict__ V, ushortT* __restrict__ Vt)
{
    __shared__ __align__(16) ushortT T[64 * 68];
    const int tid = threadIdx.x;
    const size_t bh = (size_t)blockIdx.z * H_ + blockIdx.y;
    const int s0 = blockIdx.x * 64;

    for (int t2 = tid; t2 < 512; t2 += 256) {
        const int row = t2 >> 3, c = t2 & 7;
        *(float4*)&T[row * 68 + c * 8] =
            *(const float4*)&V[(bh * S_ + s0 + row) * HD_ + c * 8];
    }
    __syncthreads();
    for (int t2 = tid; t2 < 512; t2 += 256) {
        const int hd = t2 >> 3, c = t2 & 7;
        union { ushortT u[8]; float4 f; } tmp;
        #pragma unroll
        for (int i = 0; i < 8; ++i) tmp.u[i] = T[(c * 8 + i) * 68 + hd];
        *(float4*)&Vt[(bh * HD_ + hd) * S_ + s0 + c * 8] = tmp.f;
    }
}

// ---------------------------------------------------------------------------
// Flash attention, bf16 MFMA (16x16x32). Q pre-scaled bf16 [B,H,S,HD];
// K bf16 [B,H,S,HD]; Vt bf16 [B,H,HD,S]; mask f32 [B,S]; out bf16 [B,S,D].
// Block = 256 thr = 4 waves; 64 Q rows/block; KV tiles of 64.
// ---------------------------------------------------------------------------
__global__ __launch_bounds__(256)
void attn_mfma(const ushortT* __restrict__ Q, const ushortT* __restrict__ K,
               const ushortT* __restrict__ Vt, const float* __restrict__ mask,
               ushortT* __restrict__ out)
{
    __shared__ __align__(16) ushortT Ks[64 * 64];
    __shared__ __align__(16) ushortT Vs[64 * 64];
    __shared__ __align__(16) ushortT Ps[4][16 * 88];
    __shared__ float Ms[S_];

    const int tid  = threadIdx.x;
    const int lane = tid & 63;
    const int wave = tid >> 6;
    const int lr   = lane & 15;
    const int lg   = lane >> 4;
    const int q0   = blockIdx.x * 64;
    const int h    = blockIdx.y;
    const int b    = blockIdx.z;
    const size_t bh = (size_t)b * H_ + h;

    for (int f = tid; f < 512; f += 256)
        *(float4*)&Ms[f * 4] = *(const float4*)&mask[(size_t)b * S_ + f * 4];

    const ushortT* Qg = Q + (bh * S_ + q0 + wave * 16 + lr) * HD_;
    bf16x8 qf[2];
    qf[0] = __builtin_bit_cast(bf16x8, *(const float4*)(Qg + lg * 8));
    qf[1] = __builtin_bit_cast(bf16x8, *(const float4*)(Qg + 32 + lg * 8));

    const ushortT* Kg = K  + bh * S_ * HD_;
    const ushortT* Vg = Vt + bh * HD_ * S_;

    f32x4 acc[4];
    float mrun[4], lrun[4];
    #pragma unroll
    for (int j = 0; j < 4; ++j) {
        acc[j] = (f32x4){0.f, 0.f, 0.f, 0.f};
        mrun[j] = -INFINITY;
        lrun[j] = 0.f;
    }

    for (int kt = 0; kt < S_ / 64; ++kt) {
        const int k0 = kt * 64;
        __syncthreads();
        #pragma unroll
        for (int t2 = tid; t2 < 512; t2 += 256) {
            const int row = t2 >> 3, c = t2 & 7, p = c ^ (row & 7);
            *(float4*)((char*)Ks + row * 128 + p * 16) =
                *(const float4*)(Kg + (size_t)(k0 + row) * HD_ + c * 8);
            *(float4*)((char*)Vs + row * 128 + p * 16) =
                *(const float4*)(Vg + (size_t)row * S_ + k0 + c * 8);
        }
        __syncthreads();

        f32x4 s[4];
        #pragma unroll
        for (int cb = 0; cb < 4; ++cb) {
            s[cb] = (f32x4){0.f, 0.f, 0.f, 0.f};
            #pragma unroll
            for (int ks = 0; ks < 2; ++ks) {
                const int rk = cb * 16 + lr;
                const int pp = (ks * 4 + lg) ^ (rk & 7);
                bf16x8 kf = __builtin_bit_cast(bf16x8,
                    *(const float4*)((const char*)Ks + rk * 128 + pp * 16));
                s[cb] = __builtin_amdgcn_mfma_f32_16x16x32_bf16(qf[ks], kf, s[cb], 0, 0, 0);
            }
        }

        #pragma unroll
        for (int cb = 0; cb < 4; ++cb) {
            const float mv = Ms[k0 + cb * 16 + lr];
            #pragma unroll
            for (int j = 0; j < 4; ++j) s[cb][j] += mv;
        }
        float fac[4];
        #pragma unroll
        for (int j = 0; j < 4; ++j) {
            float t = fmaxf(fmaxf(s[0][j], s[1][j]), fmaxf(s[2][j], s[3][j]));
            t = fmaxf(t, __shfl_xor(t, 1));
            t = fmaxf(t, __shfl_xor(t, 2));
            t = fmaxf(t, __shfl_xor(t, 4));
            t = fmaxf(t, __shfl_xor(t, 8));
            const float mn = fmaxf(mrun[j], t);
            fac[j] = __expf(mrun[j] - mn);
            mrun[j] = mn;
        }
        float psum[4] = {0.f, 0.f, 0.f, 0.f};
        #pragma unroll
        for (int cb = 0; cb < 4; ++cb) {
            #pragma unroll
            for (int j = 0; j < 4; ++j) {
                const float p = __expf(s[cb][j] - mrun[j]);
                s[cb][j] = p;
                psum[j] += p;
            }
        }
        #pragma unroll
        for (int j = 0; j < 4; ++j) {
            float ps = psum[j];
            ps += __shfl_xor(ps, 1);
            ps += __shfl_xor(ps, 2);
            ps += __shfl_xor(ps, 4);
            ps += __shfl_xor(ps, 8);
            lrun[j] = lrun[j] * fac[j] + ps;
        }
        #pragma unroll
        for (int cb = 0; cb < 4; ++cb)
            #pragma unroll
            for (int j = 0; j < 4; ++j) acc[cb][j] *= fac[j];

        #pragma unroll
        for (int cb = 0; cb < 4; ++cb) {
            #pragma unroll
            for (int j = 0; j < 4; ++j)
                Ps[wave][(lg * 4 + j) * 88 + cb * 16 + lr] = f2bf(s[cb][j]);
        }

        #pragma unroll
        for (int ks2 = 0; ks2 < 2; ++ks2) {
            bf16x8 pf = __builtin_bit_cast(bf16x8,
                *(const float4*)((const char*)&Ps[wave][0] + lr * 176 + (ks2 * 4 + lg) * 16));
            #pragma unroll
            for (int cb = 0; cb < 4; ++cb) {
                const int rv = cb * 16 + lr;
                const int pp = (ks2 * 4 + lg) ^ (rv & 7);
                bf16x8 vf = __builtin_bit_cast(bf16x8,
                    *(const float4*)((const char*)Vs + rv * 128 + pp * 16));
                acc[cb] = __builtin_amdgcn_mfma_f32_16x16x32_bf16(pf, vf, acc[cb], 0, 0, 0);
            }
        }
    }

    float inv[4];
    #pragma unroll
    for (int j = 0; j < 4; ++j) inv[j] = 1.f / lrun[j];
    #pragma unroll
    for (int cb = 0; cb < 4; ++cb) {
        #pragma unroll
        for (int j = 0; j < 4; ++j) {
            const size_t row = (size_t)b * S_ + q0 + wave * 16 + lg * 4 + j;
            out[row * D_ + h * HD_ + cb * 16 + lr] = f2bf(acc[cb][j] * inv[j]);
        }
    }
}

// ---------------------------------------------------------------------------
extern "C" void kernel_launch(void* const* d_in, const int* in_sizes, int n_in,
                              void* d_out, int out_size, void* d_ws, size_t ws_size,
                              hipStream_t stream)
{
    const float* x    = (const float*)d_in[0];
    const float* mask = (const float*)d_in[1];
    const float* Wq   = (const float*)d_in[2];
    const float* bq   = (const float*)d_in[3];
    const float* Wk   = (const float*)d_in[4];
    const float* bk   = (const float*)d_in[5];
    const float* Wv   = (const float*)d_in[6];
    const float* bv   = (const float*)d_in[7];
    const float* Wo   = (const float*)d_in[8];
    const float* bo   = (const float*)d_in[9];
    float* out = (float*)d_out;

    const size_t NE = (size_t)B_ * S_ * D_;  // 6291456
    ushortT* xb  = (ushortT*)d_ws;
    ushortT* qb  = xb + NE;
    ushortT* kb  = qb + NE;
    ushortT* vb  = kb + NE;
    ushortT* vtb = vb + NE;
    ushortT* ab  = vtb + NE;
    ushortT* wt4 = ab + NE;                  // 4 * 768 * 768

    convert_f32_bf16<<<NE / 2048, 256, 0, stream>>>(x, xb);
    transpose_w<<<dim3(12, 12, 4), 256, 0, stream>>>(Wq, Wk, Wv, Wo, wt4);

    qkv_gemm<<<dim3(M_ / 128, 12, 3), 256, 0, stream>>>(
        xb, wt4, bq, bk, bv, qb, kb, vb);

    transpose_v<<<dim3(S_ / 64, H_, B_), 256, 0, stream>>>(vb, vtb);

    attn_mfma<<<dim3(S_ / 64, H_, B_), 256, 0, stream>>>(qb, kb, vtb, mask, ab);

    o_gemm<<<dim3(M_ / 128, 12), 256, 0, stream>>>(
        ab, wt4 + 3 * 768 * 768, bo, out);
}

// Round 4
// 195.454 us; speedup vs baseline: 12.7807x; 1.2564x over previous
//
#include <hip/hip_runtime.h>
#include <cmath>

#define B_ 4
#define S_ 2048
#define D_ 768
#define H_ 12
#define HD_ 64
#define SCALE_ 0.125f
#define M_ 8192

typedef unsigned short ushortT;
typedef __attribute__((ext_vector_type(8))) __bf16 bf16x8;
typedef __attribute__((ext_vector_type(4))) float f32x4;

typedef __attribute__((address_space(1))) const void glb_cv;
typedef __attribute__((address_space(3))) void lds_v;

__device__ inline ushortT f2bf(float f) {
    return __builtin_bit_cast(ushortT, (__bf16)f);
}

__device__ inline void gload_lds16(const void* g, void* l) {
    __builtin_amdgcn_global_load_lds((glb_cv*)g, (lds_v*)l, 16, 0, 0);
}

// ---------------------------------------------------------------------------
// convert x fp32 -> bf16, 8 el/thread
// ---------------------------------------------------------------------------
__global__ __launch_bounds__(256)
void convert_f32_bf16(const float* __restrict__ in, ushortT* __restrict__ out)
{
    const size_t i = ((size_t)blockIdx.x * 256 + threadIdx.x) * 8;
    float4 a = *(const float4*)(in + i);
    float4 b = *(const float4*)(in + i + 4);
    union { ushortT u[8]; float4 f; } o;
    o.u[0] = f2bf(a.x); o.u[1] = f2bf(a.y); o.u[2] = f2bf(a.z); o.u[3] = f2bf(a.w);
    o.u[4] = f2bf(b.x); o.u[5] = f2bf(b.y); o.u[6] = f2bf(b.z); o.u[7] = f2bf(b.w);
    *(float4*)(out + i) = o.f;
}

// ---------------------------------------------------------------------------
// transpose+convert W [768,768] f32 -> Wt [768,768] bf16 (Wt[n][k] = W[k][n]).
// ---------------------------------------------------------------------------
__global__ __launch_bounds__(256)
void transpose_w(const float* __restrict__ W0, const float* __restrict__ W1,
                 const float* __restrict__ W2, const float* __restrict__ W3,
                 ushortT* __restrict__ wt4)
{
    const float* W = (blockIdx.z == 0) ? W0 : (blockIdx.z == 1) ? W1
                   : (blockIdx.z == 2) ? W2 : W3;
    ushortT* o = wt4 + (size_t)blockIdx.z * 768 * 768;
    __shared__ float T[64][65];
    const int tid = threadIdx.x;
    const int k0 = blockIdx.x * 64, n0 = blockIdx.y * 64;

    for (int t = tid; t < 1024; t += 256) {
        const int r = t >> 4, c4 = (t & 15) << 2;
        float4 v = *(const float4*)&W[(size_t)(k0 + r) * 768 + n0 + c4];
        T[r][c4 + 0] = v.x; T[r][c4 + 1] = v.y;
        T[r][c4 + 2] = v.z; T[r][c4 + 3] = v.w;
    }
    __syncthreads();
    for (int t = tid; t < 1024; t += 256) {
        const int r = t >> 4, c4 = (t & 15) << 2;
        union { ushortT u[4]; unsigned long long v; } ov;
        ov.u[0] = f2bf(T[c4 + 0][r]); ov.u[1] = f2bf(T[c4 + 1][r]);
        ov.u[2] = f2bf(T[c4 + 2][r]); ov.u[3] = f2bf(T[c4 + 3][r]);
        *(unsigned long long*)&o[(size_t)(n0 + r) * 768 + k0 + c4] = ov.v;
    }
}

// ---------------------------------------------------------------------------
// MFMA GEMM core: C[128x64] = A[m0..,768] * Bt[n0..,768]^T  (bf16, fp32 acc)
// ---------------------------------------------------------------------------
__device__ inline void gemm_core_128x64(
    const ushortT* __restrict__ A, const ushortT* __restrict__ Bt,
    ushortT* As, ushortT* Bs, int m0, int n0, f32x4 acc[4][2])
{
    const int tid  = threadIdx.x;
    const int lane = tid & 63;
    const int wave = tid >> 6;
    const int lr = lane & 15, lg = lane >> 4;
    const int wr = wave >> 1, wc = wave & 1;

    #pragma unroll
    for (int mi = 0; mi < 4; ++mi)
        #pragma unroll
        for (int ni = 0; ni < 2; ++ni)
            acc[mi][ni] = (f32x4){0.f, 0.f, 0.f, 0.f};

    #pragma unroll 1
    for (int k0 = 0; k0 < 768; k0 += 64) {
        __syncthreads();
        #pragma unroll
        for (int it = 0; it < 4; ++it) {
            const int ci = it * 256 + tid;
            const int row = ci >> 3, c = ci & 7;
            const int sc = c ^ (row & 7);
            gload_lds16(A + (size_t)(m0 + row) * 768 + k0 + sc * 8,
                        As + (size_t)(it * 256 + wave * 64) * 8);
        }
        #pragma unroll
        for (int it = 0; it < 2; ++it) {
            const int ci = it * 256 + tid;
            const int row = ci >> 3, c = ci & 7;
            const int sc = c ^ (row & 7);
            gload_lds16(Bt + (size_t)(n0 + row) * 768 + k0 + sc * 8,
                        Bs + (size_t)(it * 256 + wave * 64) * 8);
        }
        __syncthreads();

        #pragma unroll
        for (int ks = 0; ks < 2; ++ks) {
            bf16x8 af[4], bfr[2];
            #pragma unroll
            for (int mi = 0; mi < 4; ++mi) {
                const int row = wr * 64 + mi * 16 + lr;
                const int ch = (ks * 4 + lg) ^ (row & 7);
                af[mi] = __builtin_bit_cast(bf16x8, *(const float4*)(As + row * 64 + ch * 8));
            }
            #pragma unroll
            for (int ni = 0; ni < 2; ++ni) {
                const int row = wc * 32 + ni * 16 + lr;
                const int ch = (ks * 4 + lg) ^ (row & 7);
                bfr[ni] = __builtin_bit_cast(bf16x8, *(const float4*)(Bs + row * 64 + ch * 8));
            }
            #pragma unroll
            for (int mi = 0; mi < 4; ++mi)
                #pragma unroll
                for (int ni = 0; ni < 2; ++ni)
                    acc[mi][ni] = __builtin_amdgcn_mfma_f32_16x16x32_bf16(
                        af[mi], bfr[ni], acc[mi][ni], 0, 0, 0);
        }
    }
}

// ---------------------------------------------------------------------------
// QKV fused GEMM: z selects {Wq,Wk,Wv}; writes bf16 split-head [B,H,S,HD].
// ---------------------------------------------------------------------------
__global__ __launch_bounds__(256)
void qkv_gemm(const ushortT* __restrict__ xb, const ushortT* __restrict__ wt4,
              const float* __restrict__ bq, const float* __restrict__ bk,
              const float* __restrict__ bv,
              ushortT* __restrict__ qb, ushortT* __restrict__ kb,
              ushortT* __restrict__ vb)
{
    __shared__ __align__(16) ushortT As[128 * 64];
    __shared__ __align__(16) ushortT Bs[64 * 64];
    const int z = blockIdx.z;
    const ushortT* Wt = wt4 + (size_t)z * 768 * 768;
    const float* bias = (z == 0) ? bq : (z == 1) ? bk : bv;
    ushortT* out = (z == 0) ? qb : (z == 1) ? kb : vb;
    const float scale = (z == 0) ? SCALE_ : 1.0f;

    const int m0 = blockIdx.x * 128, n0 = blockIdx.y * 64;
    f32x4 acc[4][2];
    gemm_core_128x64(xb, Wt, As, Bs, m0, n0, acc);

    const int tid = threadIdx.x;
    const int lane = tid & 63, wave = tid >> 6;
    const int lr = lane & 15, lg = lane >> 4;
    const int wr = wave >> 1, wc = wave & 1;
    const int h = n0 >> 6;

    #pragma unroll
    for (int ni = 0; ni < 2; ++ni) {
        const int nn = wc * 32 + ni * 16 + lr;
        const float bb = bias[n0 + nn];
        #pragma unroll
        for (int mi = 0; mi < 4; ++mi) {
            #pragma unroll
            for (int j = 0; j < 4; ++j) {
                const int m = m0 + wr * 64 + mi * 16 + lg * 4 + j;
                const int b = m >> 11, s = m & 2047;
                out[(((size_t)b * H_ + h) * S_ + s) * HD_ + nn] =
                    f2bf((acc[mi][ni][j] + bb) * scale);
            }
        }
    }
}

// ---------------------------------------------------------------------------
// Output projection: ab bf16 [M,768] x Wo^T -> fp32 [M,768] + bias.
// ---------------------------------------------------------------------------
__global__ __launch_bounds__(256)
void o_gemm(const ushortT* __restrict__ ab, const ushortT* __restrict__ wto,
            const float* __restrict__ bo, float* __restrict__ out)
{
    __shared__ __align__(16) ushortT As[128 * 64];
    __shared__ __align__(16) ushortT Bs[64 * 64];
    const int m0 = blockIdx.x * 128, n0 = blockIdx.y * 64;
    f32x4 acc[4][2];
    gemm_core_128x64(ab, wto, As, Bs, m0, n0, acc);

    const int tid = threadIdx.x;
    const int lane = tid & 63, wave = tid >> 6;
    const int lr = lane & 15, lg = lane >> 4;
    const int wr = wave >> 1, wc = wave & 1;

    #pragma unroll
    for (int ni = 0; ni < 2; ++ni) {
        const int n = n0 + wc * 32 + ni * 16 + lr;
        const float bb = bo[n];
        #pragma unroll
        for (int mi = 0; mi < 4; ++mi) {
            #pragma unroll
            for (int j = 0; j < 4; ++j) {
                const int m = m0 + wr * 64 + mi * 16 + lg * 4 + j;
                out[(size_t)m * 768 + n] = acc[mi][ni][j] + bb;
            }
        }
    }
}

// ---------------------------------------------------------------------------
// Transpose V [B,H,S,HD] bf16 -> Vt [B,H,HD,S] bf16.
// ---------------------------------------------------------------------------
__global__ __launch_bounds__(256)
void transpose_v(const ushortT* __restrict__ V, ushortT* __restrict__ Vt)
{
    __shared__ __align__(16) ushortT T[64 * 68];
    const int tid = threadIdx.x;
    const size_t bh = (size_t)blockIdx.z * H_ + blockIdx.y;
    const int s0 = blockIdx.x * 64;

    for (int t2 = tid; t2 < 512; t2 += 256) {
        const int row = t2 >> 3, c = t2 & 7;
        *(float4*)&T[row * 68 + c * 8] =
            *(const float4*)&V[(bh * S_ + s0 + row) * HD_ + c * 8];
    }
    __syncthreads();
    for (int t2 = tid; t2 < 512; t2 += 256) {
        const int hd = t2 >> 3, c = t2 & 7;
        union { ushortT u[8]; float4 f; } tmp;
        #pragma unroll
        for (int i = 0; i < 8; ++i) tmp.u[i] = T[(c * 8 + i) * 68 + hd];
        *(float4*)&Vt[(bh * HD_ + hd) * S_ + s0 + c * 8] = tmp.f;
    }
}

// ---------------------------------------------------------------------------
// Flash attention, bf16 MFMA, SWAPPED QK^T (lane owns one q-row of scores).
// Q pre-scaled bf16 [B,H,S,HD]; K bf16 [B,H,S,HD]; Vt bf16 [B,H,HD,S];
// mask f32 [B,S]; out bf16 [B,S,D].
// Block = 256 thr = 4 waves; 64 Q rows/block; KV tiles of 64, double-buffered
// via global_load_lds (pre-swizzled source, linear dest, swizzled ds_read).
// ---------------------------------------------------------------------------
__global__ __launch_bounds__(256)
void attn_mfma(const ushortT* __restrict__ Q, const ushortT* __restrict__ K,
               const ushortT* __restrict__ Vt, const float* __restrict__ mask,
               ushortT* __restrict__ out)
{
    __shared__ __align__(16) ushortT Ks[2][64 * 64];
    __shared__ __align__(16) ushortT Vs[2][64 * 64];
    __shared__ __align__(16) ushortT Ps[4][16 * 88];
    __shared__ float Ms[S_];

    const int tid  = threadIdx.x;
    const int lane = tid & 63;
    const int wave = tid >> 6;
    const int lr   = lane & 15;
    const int lg   = lane >> 4;
    const int q0   = blockIdx.x * 64;
    const int h    = blockIdx.y;
    const int b    = blockIdx.z;
    const size_t bh = (size_t)b * H_ + h;

    for (int f = tid; f < 512; f += 256)
        *(float4*)&Ms[f * 4] = *(const float4*)&mask[(size_t)b * S_ + f * 4];

    // Q B-fragment (col = q = lr, k = 8*lg + i), kept in registers
    const ushortT* Qg = Q + (bh * S_ + q0 + wave * 16 + lr) * HD_;
    bf16x8 qf[2];
    qf[0] = __builtin_bit_cast(bf16x8, *(const float4*)(Qg + lg * 8));
    qf[1] = __builtin_bit_cast(bf16x8, *(const float4*)(Qg + 32 + lg * 8));

    const ushortT* Kg = K  + bh * S_ * HD_;
    const ushortT* Vg = Vt + bh * HD_ * S_;

    f32x4 acc[4];
    #pragma unroll
    for (int cb = 0; cb < 4; ++cb) acc[cb] = (f32x4){0.f, 0.f, 0.f, 0.f};
    float mrun = -INFINITY, lrun = 0.f;

    // ---- DMA staging: pre-swizzled source, linear LDS dest (rule #21) ----
    auto stage = [&](int bsel, int k0) {
        #pragma unroll
        for (int it = 0; it < 2; ++it) {
            const int ci = it * 256 + tid;
            const int row = ci >> 3, c = ci & 7, sc = c ^ (row & 7);
            gload_lds16(Kg + (size_t)(k0 + row) * HD_ + sc * 8,
                        &Ks[bsel][(it * 256 + wave * 64) * 8]);
        }
        #pragma unroll
        for (int it = 0; it < 2; ++it) {
            const int ci = it * 256 + tid;
            const int row = ci >> 3, c = ci & 7, sc = c ^ (row & 7);
            gload_lds16(Vg + (size_t)row * S_ + k0 + sc * 8,
                        &Vs[bsel][(it * 256 + wave * 64) * 8]);
        }
    };

    stage(0, 0);
    __syncthreads();   // drains stage DMA + Ms writes

    for (int kt = 0; kt < S_ / 64; ++kt) {
        const int k0 = kt * 64;
        const int buf = kt & 1;
        if (kt + 1 < S_ / 64) stage(buf ^ 1, k0 + 64);   // prefetch next tile

        // ---- QK^T swapped: s[cb] = S^T[key=cb*16+lg*4+j][q=lr] ----
        bf16x8 kf[4][2];
        #pragma unroll
        for (int cb = 0; cb < 4; ++cb) {
            #pragma unroll
            for (int ks = 0; ks < 2; ++ks) {
                const int rk = cb * 16 + lr;
                const int pp = (ks * 4 + lg) ^ (rk & 7);
                kf[cb][ks] = __builtin_bit_cast(bf16x8,
                    *(const float4*)(&Ks[buf][rk * 64 + pp * 8]));
            }
        }
        f32x4 s[4];
        #pragma unroll
        for (int cb = 0; cb < 4; ++cb) s[cb] = (f32x4){0.f, 0.f, 0.f, 0.f};
        __builtin_amdgcn_s_setprio(1);
        #pragma unroll
        for (int cb = 0; cb < 4; ++cb)
            #pragma unroll
            for (int ks = 0; ks < 2; ++ks)
                s[cb] = __builtin_amdgcn_mfma_f32_16x16x32_bf16(
                    kf[cb][ks], qf[ks], s[cb], 0, 0, 0);
        __builtin_amdgcn_s_setprio(0);

        // ---- mask (per key = per reg) ----
        #pragma unroll
        for (int cb = 0; cb < 4; ++cb) {
            float4 mv = *(const float4*)&Ms[k0 + cb * 16 + lg * 4];
            s[cb][0] += mv.x; s[cb][1] += mv.y;
            s[cb][2] += mv.z; s[cb][3] += mv.w;
        }

        // ---- online softmax, scalar stats (lane owns q-row lr) ----
        float t = s[0][0];
        #pragma unroll
        for (int cb = 0; cb < 4; ++cb)
            #pragma unroll
            for (int j = 0; j < 4; ++j) t = fmaxf(t, s[cb][j]);
        t = fmaxf(t, __shfl_xor(t, 16));
        t = fmaxf(t, __shfl_xor(t, 32));

        const bool need = !__all(t <= mrun + 8.f);   // T13 defer-max
        float fac = 1.f;
        if (need) {
            const float mn = fmaxf(mrun, t);
            fac = __expf(mrun - mn);                 // first tile: exp(-inf)=0
            mrun = mn;
        }

        float psum = 0.f;
        ushort4 pw[4];
        #pragma unroll
        for (int cb = 0; cb < 4; ++cb) {
            float p0 = __expf(s[cb][0] - mrun);
            float p1 = __expf(s[cb][1] - mrun);
            float p2 = __expf(s[cb][2] - mrun);
            float p3 = __expf(s[cb][3] - mrun);
            psum += (p0 + p1) + (p2 + p3);
            pw[cb].x = f2bf(p0); pw[cb].y = f2bf(p1);
            pw[cb].z = f2bf(p2); pw[cb].w = f2bf(p3);
        }
        psum += __shfl_xor(psum, 16);
        psum += __shfl_xor(psum, 32);
        lrun = lrun * fac + psum;

        if (need) {
            float fr[4];
            #pragma unroll
            for (int j = 0; j < 4; ++j) fr[j] = __shfl(fac, lg * 4 + j);
            #pragma unroll
            for (int cb = 0; cb < 4; ++cb)
                #pragma unroll
                for (int j = 0; j < 4; ++j) acc[cb][j] *= fr[j];
        }

        // ---- P write: P[q=lr][key=cb*16+lg*4+{0..3}] as one b64 ----
        #pragma unroll
        for (int cb = 0; cb < 4; ++cb)
            *(ushort4*)&Ps[wave][lr * 88 + cb * 16 + lg * 4] = pw[cb];

        // ---- PV: O[16q x 64hd] += P[16 x 64] * Vt[64hd x 64keys]^T ----
        bf16x8 pf[2];
        #pragma unroll
        for (int ks2 = 0; ks2 < 2; ++ks2)
            pf[ks2] = __builtin_bit_cast(bf16x8,
                *(const float4*)(&Ps[wave][lr * 88 + ks2 * 32 + lg * 8]));
        bf16x8 vf[4][2];
        #pragma unroll
        for (int cb = 0; cb < 4; ++cb) {
            #pragma unroll
            for (int ks2 = 0; ks2 < 2; ++ks2) {
                const int rv = cb * 16 + lr;
                const int pp = (ks2 * 4 + lg) ^ (rv & 7);
                vf[cb][ks2] = __builtin_bit_cast(bf16x8,
                    *(const float4*)(&Vs[buf][rv * 64 + pp * 8]));
            }
        }
        __builtin_amdgcn_s_setprio(1);
        #pragma unroll
        for (int cb = 0; cb < 4; ++cb)
            #pragma unroll
            for (int ks2 = 0; ks2 < 2; ++ks2)
                acc[cb] = __builtin_amdgcn_mfma_f32_16x16x32_bf16(
                    pf[ks2], vf[cb][ks2], acc[cb], 0, 0, 0);
        __builtin_amdgcn_s_setprio(0);

        __syncthreads();   // drains prefetch DMA (vmcnt 0) + LDS; swap buffers
    }

    // ---- epilogue: acc rows q=lg*4+j, col hd=cb*16+lr ----
    const float inv = 1.f / lrun;          // per-lane q = lr
    float ir[4];
    #pragma unroll
    for (int j = 0; j < 4; ++j) ir[j] = __shfl(inv, lg * 4 + j);
    #pragma unroll
    for (int cb = 0; cb < 4; ++cb) {
        #pragma unroll
        for (int j = 0; j < 4; ++j) {
            const size_t row = (size_t)b * S_ + q0 + wave * 16 + lg * 4 + j;
            out[row * D_ + h * HD_ + cb * 16 + lr] = f2bf(acc[cb][j] * ir[j]);
        }
    }
}

// ---------------------------------------------------------------------------
extern "C" void kernel_launch(void* const* d_in, const int* in_sizes, int n_in,
                              void* d_out, int out_size, void* d_ws, size_t ws_size,
                              hipStream_t stream)
{
    const float* x    = (const float*)d_in[0];
    const float* mask = (const float*)d_in[1];
    const float* Wq   = (const float*)d_in[2];
    const float* bq   = (const float*)d_in[3];
    const float* Wk   = (const float*)d_in[4];
    const float* bk   = (const float*)d_in[5];
    const float* Wv   = (const float*)d_in[6];
    const float* bv   = (const float*)d_in[7];
    const float* Wo   = (const float*)d_in[8];
    const float* bo   = (const float*)d_in[9];
    float* out = (float*)d_out;

    const size_t NE = (size_t)B_ * S_ * D_;  // 6291456
    ushortT* xb  = (ushortT*)d_ws;
    ushortT* qb  = xb + NE;
    ushortT* kb  = qb + NE;
    ushortT* vb  = kb + NE;
    ushortT* vtb = vb + NE;
    ushortT* ab  = vtb + NE;
    ushortT* wt4 = ab + NE;                  // 4 * 768 * 768

    convert_f32_bf16<<<NE / 2048, 256, 0, stream>>>(x, xb);
    transpose_w<<<dim3(12, 12, 4), 256, 0, stream>>>(Wq, Wk, Wv, Wo, wt4);

    qkv_gemm<<<dim3(M_ / 128, 12, 3), 256, 0, stream>>>(
        xb, wt4, bq, bk, bv, qb, kb, vb);

    transpose_v<<<dim3(S_ / 64, H_, B_), 256, 0, stream>>>(vb, vtb);

    attn_mfma<<<dim3(S_ / 64, H_, B_), 256, 0, stream>>>(qb, kb, vtb, mask, ab);

    o_gemm<<<dim3(M_ / 128, 12), 256, 0, stream>>>(
        ab, wt4 + 3 * 768 * 768, bo, out);
}

// Round 5
// 187.427 us; speedup vs baseline: 13.3281x; 1.0428x over previous
//
#include <hip/hip_runtime.h>
#include <cmath>

#define B_ 4
#define S_ 2048
#define D_ 768
#define H_ 12
#define HD_ 64
#define SCALE_ 0.125f
#define LOG2E_ 1.4426950408889634f
#define M_ 8192

typedef unsigned short ushortT;
typedef __attribute__((ext_vector_type(8))) __bf16 bf16x8;
typedef __attribute__((ext_vector_type(4))) float f32x4;

typedef __attribute__((address_space(1))) const void glb_cv;
typedef __attribute__((address_space(3))) void lds_v;

__device__ inline ushortT f2bf(float f) {
    return __builtin_bit_cast(ushortT, (__bf16)f);
}

__device__ inline void gload_lds16(const void* g, void* l) {
    __builtin_amdgcn_global_load_lds((glb_cv*)g, (lds_v*)l, 16, 0, 0);
}

// ---------------------------------------------------------------------------
// convert x fp32 -> bf16, 8 el/thread
// ---------------------------------------------------------------------------
__global__ __launch_bounds__(256)
void convert_f32_bf16(const float* __restrict__ in, ushortT* __restrict__ out)
{
    const size_t i = ((size_t)blockIdx.x * 256 + threadIdx.x) * 8;
    float4 a = *(const float4*)(in + i);
    float4 b = *(const float4*)(in + i + 4);
    union { ushortT u[8]; float4 f; } o;
    o.u[0] = f2bf(a.x); o.u[1] = f2bf(a.y); o.u[2] = f2bf(a.z); o.u[3] = f2bf(a.w);
    o.u[4] = f2bf(b.x); o.u[5] = f2bf(b.y); o.u[6] = f2bf(b.z); o.u[7] = f2bf(b.w);
    *(float4*)(out + i) = o.f;
}

// ---------------------------------------------------------------------------
// transpose+convert W [768,768] f32 -> Wt [768,768] bf16 (Wt[n][k] = W[k][n]).
// ---------------------------------------------------------------------------
__global__ __launch_bounds__(256)
void transpose_w(const float* __restrict__ W0, const float* __restrict__ W1,
                 const float* __restrict__ W2, const float* __restrict__ W3,
                 ushortT* __restrict__ wt4)
{
    const float* W = (blockIdx.z == 0) ? W0 : (blockIdx.z == 1) ? W1
                   : (blockIdx.z == 2) ? W2 : W3;
    ushortT* o = wt4 + (size_t)blockIdx.z * 768 * 768;
    __shared__ float T[64][65];
    const int tid = threadIdx.x;
    const int k0 = blockIdx.x * 64, n0 = blockIdx.y * 64;

    for (int t = tid; t < 1024; t += 256) {
        const int r = t >> 4, c4 = (t & 15) << 2;
        float4 v = *(const float4*)&W[(size_t)(k0 + r) * 768 + n0 + c4];
        T[r][c4 + 0] = v.x; T[r][c4 + 1] = v.y;
        T[r][c4 + 2] = v.z; T[r][c4 + 3] = v.w;
    }
    __syncthreads();
    for (int t = tid; t < 1024; t += 256) {
        const int r = t >> 4, c4 = (t & 15) << 2;
        union { ushortT u[4]; unsigned long long v; } ov;
        ov.u[0] = f2bf(T[c4 + 0][r]); ov.u[1] = f2bf(T[c4 + 1][r]);
        ov.u[2] = f2bf(T[c4 + 2][r]); ov.u[3] = f2bf(T[c4 + 3][r]);
        *(unsigned long long*)&o[(size_t)(n0 + r) * 768 + k0 + c4] = ov.v;
    }
}

// ---------------------------------------------------------------------------
// MFMA GEMM core: C[128x64] = A[m0..,768] * Bt[n0..,768]^T  (bf16, fp32 acc)
// ---------------------------------------------------------------------------
__device__ inline void gemm_core_128x64(
    const ushortT* __restrict__ A, const ushortT* __restrict__ Bt,
    ushortT* As, ushortT* Bs, int m0, int n0, f32x4 acc[4][2])
{
    const int tid  = threadIdx.x;
    const int lane = tid & 63;
    const int wave = tid >> 6;
    const int lr = lane & 15, lg = lane >> 4;
    const int wr = wave >> 1, wc = wave & 1;

    #pragma unroll
    for (int mi = 0; mi < 4; ++mi)
        #pragma unroll
        for (int ni = 0; ni < 2; ++ni)
            acc[mi][ni] = (f32x4){0.f, 0.f, 0.f, 0.f};

    #pragma unroll 1
    for (int k0 = 0; k0 < 768; k0 += 64) {
        __syncthreads();
        #pragma unroll
        for (int it = 0; it < 4; ++it) {
            const int ci = it * 256 + tid;
            const int row = ci >> 3, c = ci & 7;
            const int sc = c ^ (row & 7);
            gload_lds16(A + (size_t)(m0 + row) * 768 + k0 + sc * 8,
                        As + (size_t)(it * 256 + wave * 64) * 8);
        }
        #pragma unroll
        for (int it = 0; it < 2; ++it) {
            const int ci = it * 256 + tid;
            const int row = ci >> 3, c = ci & 7;
            const int sc = c ^ (row & 7);
            gload_lds16(Bt + (size_t)(n0 + row) * 768 + k0 + sc * 8,
                        Bs + (size_t)(it * 256 + wave * 64) * 8);
        }
        __syncthreads();

        #pragma unroll
        for (int ks = 0; ks < 2; ++ks) {
            bf16x8 af[4], bfr[2];
            #pragma unroll
            for (int mi = 0; mi < 4; ++mi) {
                const int row = wr * 64 + mi * 16 + lr;
                const int ch = (ks * 4 + lg) ^ (row & 7);
                af[mi] = __builtin_bit_cast(bf16x8, *(const float4*)(As + row * 64 + ch * 8));
            }
            #pragma unroll
            for (int ni = 0; ni < 2; ++ni) {
                const int row = wc * 32 + ni * 16 + lr;
                const int ch = (ks * 4 + lg) ^ (row & 7);
                bfr[ni] = __builtin_bit_cast(bf16x8, *(const float4*)(Bs + row * 64 + ch * 8));
            }
            #pragma unroll
            for (int mi = 0; mi < 4; ++mi)
                #pragma unroll
                for (int ni = 0; ni < 2; ++ni)
                    acc[mi][ni] = __builtin_amdgcn_mfma_f32_16x16x32_bf16(
                        af[mi], bfr[ni], acc[mi][ni], 0, 0, 0);
        }
    }
}

// ---------------------------------------------------------------------------
// QKV fused GEMM: z selects {Wq,Wk,Wv}; writes bf16 split-head [B,H,S,HD].
// Q is pre-scaled by SCALE*log2e (attn works in exp2 domain).
// ---------------------------------------------------------------------------
__global__ __launch_bounds__(256)
void qkv_gemm(const ushortT* __restrict__ xb, const ushortT* __restrict__ wt4,
              const float* __restrict__ bq, const float* __restrict__ bk,
              const float* __restrict__ bv,
              ushortT* __restrict__ qb, ushortT* __restrict__ kb,
              ushortT* __restrict__ vb)
{
    __shared__ __align__(16) ushortT As[128 * 64];
    __shared__ __align__(16) ushortT Bs[64 * 64];
    const int z = blockIdx.z;
    const ushortT* Wt = wt4 + (size_t)z * 768 * 768;
    const float* bias = (z == 0) ? bq : (z == 1) ? bk : bv;
    ushortT* out = (z == 0) ? qb : (z == 1) ? kb : vb;
    const float scale = (z == 0) ? (SCALE_ * LOG2E_) : 1.0f;

    const int m0 = blockIdx.x * 128, n0 = blockIdx.y * 64;
    f32x4 acc[4][2];
    gemm_core_128x64(xb, Wt, As, Bs, m0, n0, acc);

    const int tid = threadIdx.x;
    const int lane = tid & 63, wave = tid >> 6;
    const int lr = lane & 15, lg = lane >> 4;
    const int wr = wave >> 1, wc = wave & 1;
    const int h = n0 >> 6;

    #pragma unroll
    for (int ni = 0; ni < 2; ++ni) {
        const int nn = wc * 32 + ni * 16 + lr;
        const float bb = bias[n0 + nn];
        #pragma unroll
        for (int mi = 0; mi < 4; ++mi) {
            #pragma unroll
            for (int j = 0; j < 4; ++j) {
                const int m = m0 + wr * 64 + mi * 16 + lg * 4 + j;
                const int b = m >> 11, s = m & 2047;
                out[(((size_t)b * H_ + h) * S_ + s) * HD_ + nn] =
                    f2bf((acc[mi][ni][j] + bb) * scale);
            }
        }
    }
}

// ---------------------------------------------------------------------------
// Output projection: ab bf16 [M,768] x Wo^T -> fp32 [M,768] + bias.
// ---------------------------------------------------------------------------
__global__ __launch_bounds__(256)
void o_gemm(const ushortT* __restrict__ ab, const ushortT* __restrict__ wto,
            const float* __restrict__ bo, float* __restrict__ out)
{
    __shared__ __align__(16) ushortT As[128 * 64];
    __shared__ __align__(16) ushortT Bs[64 * 64];
    const int m0 = blockIdx.x * 128, n0 = blockIdx.y * 64;
    f32x4 acc[4][2];
    gemm_core_128x64(ab, wto, As, Bs, m0, n0, acc);

    const int tid = threadIdx.x;
    const int lane = tid & 63, wave = tid >> 6;
    const int lr = lane & 15, lg = lane >> 4;
    const int wr = wave >> 1, wc = wave & 1;

    #pragma unroll
    for (int ni = 0; ni < 2; ++ni) {
        const int n = n0 + wc * 32 + ni * 16 + lr;
        const float bb = bo[n];
        #pragma unroll
        for (int mi = 0; mi < 4; ++mi) {
            #pragma unroll
            for (int j = 0; j < 4; ++j) {
                const int m = m0 + wr * 64 + mi * 16 + lg * 4 + j;
                out[(size_t)m * 768 + n] = acc[mi][ni][j] + bb;
            }
        }
    }
}

// ---------------------------------------------------------------------------
// Transpose V [B,H,S,HD] bf16 -> Vt [B,H,HD,S] bf16.
// ---------------------------------------------------------------------------
__global__ __launch_bounds__(256)
void transpose_v(const ushortT* __restrict__ V, ushortT* __restrict__ Vt)
{
    __shared__ __align__(16) ushortT T[64 * 68];
    const int tid = threadIdx.x;
    const size_t bh = (size_t)blockIdx.z * H_ + blockIdx.y;
    const int s0 = blockIdx.x * 64;

    for (int t2 = tid; t2 < 512; t2 += 256) {
        const int row = t2 >> 3, c = t2 & 7;
        *(float4*)&T[row * 68 + c * 8] =
            *(const float4*)&V[(bh * S_ + s0 + row) * HD_ + c * 8];
    }
    __syncthreads();
    for (int t2 = tid; t2 < 512; t2 += 256) {
        const int hd = t2 >> 3, c = t2 & 7;
        union { ushortT u[8]; float4 f; } tmp;
        #pragma unroll
        for (int i = 0; i < 8; ++i) tmp.u[i] = T[(c * 8 + i) * 68 + hd];
        *(float4*)&Vt[(bh * HD_ + hd) * S_ + s0 + c * 8] = tmp.f;
    }
}

// ---------------------------------------------------------------------------
// Flash attention, bf16 MFMA, swapped QK^T, FIXED-MAX softmax in exp2 domain:
//   p = 2^(q'.k + mask')   (q' pre-scaled by SCALE*log2e, mask' by log2e)
// No max tracking / rescale (scores ~N(0,1)+mask, |s|<~10 => p<2^15, safe).
// Mask folded into the MFMA C-initializer (zero VALU cost).
// Row-sum l accumulated by a ones-MFMA (rows match PV acc rows; no shuffles).
// Block = 256 thr = 4 waves; 128 q/block (32/wave, 2 groups of 16);
// KV tiles of 64, double-buffered via global_load_lds (pre-swizzled source).
// Grid: 768 blocks, XCD-clustered so each (b,h)'s K/V lives on one XCD.
// ---------------------------------------------------------------------------
__global__ __launch_bounds__(256)
void attn_mfma(const ushortT* __restrict__ Q, const ushortT* __restrict__ K,
               const ushortT* __restrict__ Vt, const float* __restrict__ mask,
               ushortT* __restrict__ out)
{
    __shared__ __align__(16) ushortT Ks[2][64 * 64];
    __shared__ __align__(16) ushortT Vs[2][64 * 64];
    __shared__ __align__(16) ushortT Ps[4][16 * 88];
    __shared__ float Ms[S_];

    const int tid  = threadIdx.x;
    const int lane = tid & 63;
    const int wave = tid >> 6;
    const int lr   = lane & 15;
    const int lg   = lane >> 4;

    // XCD-clustered decode: 8 XCDs x 6 bh x 16 q-blocks (768 = 256CU x 3)
    const int gid  = blockIdx.x;
    const int xcd  = gid & 7;
    const int w    = gid >> 3;               // 0..95
    const int bh_i = xcd * 6 + (w >> 4);     // 0..47
    const int q0   = (w & 15) * 128;
    const int b    = bh_i / H_;
    const int h    = bh_i % H_;
    const size_t bh = (size_t)bh_i;

    // stage mask row, scaled to exp2 domain
    for (int f = tid; f < 512; f += 256) {
        float4 mv = *(const float4*)&mask[(size_t)b * S_ + f * 4];
        mv.x *= LOG2E_; mv.y *= LOG2E_; mv.z *= LOG2E_; mv.w *= LOG2E_;
        *(float4*)&Ms[f * 4] = mv;
    }

    // Q B-fragments for 2 q-groups (col = q = lr, k = dims), in registers
    bf16x8 qf[2][2];
    #pragma unroll
    for (int g = 0; g < 2; ++g) {
        const ushortT* Qg = Q + (bh * S_ + q0 + wave * 32 + g * 16 + lr) * HD_;
        qf[g][0] = __builtin_bit_cast(bf16x8, *(const float4*)(Qg + lg * 8));
        qf[g][1] = __builtin_bit_cast(bf16x8, *(const float4*)(Qg + 32 + lg * 8));
    }

    const ushortT* Kg = K  + bh * S_ * HD_;
    const ushortT* Vg = Vt + bh * HD_ * S_;

    // ones B-fragment for the l-sum MFMA
    bf16x8 ones;
    #pragma unroll
    for (int i = 0; i < 8; ++i) ones[i] = (__bf16)1.0f;

    f32x4 acc[2][4];     // PV out: [group][hd-block], rows = q = lg*4+j
    f32x4 accl[2];       // row-sum of P (same row mapping)
    #pragma unroll
    for (int g = 0; g < 2; ++g) {
        #pragma unroll
        for (int cb = 0; cb < 4; ++cb) acc[g][cb] = (f32x4){0.f, 0.f, 0.f, 0.f};
        accl[g] = (f32x4){0.f, 0.f, 0.f, 0.f};
    }

    auto stage = [&](int bsel, int k0) {
        #pragma unroll
        for (int it = 0; it < 2; ++it) {
            const int ci = it * 256 + tid;
            const int row = ci >> 3, c = ci & 7, sc = c ^ (row & 7);
            gload_lds16(Kg + (size_t)(k0 + row) * HD_ + sc * 8,
                        &Ks[bsel][(it * 256 + wave * 64) * 8]);
        }
        #pragma unroll
        for (int it = 0; it < 2; ++it) {
            const int ci = it * 256 + tid;
            const int row = ci >> 3, c = ci & 7, sc = c ^ (row & 7);
            gload_lds16(Vg + (size_t)row * S_ + k0 + sc * 8,
                        &Vs[bsel][(it * 256 + wave * 64) * 8]);
        }
    };

    stage(0, 0);
    __syncthreads();   // drains stage DMA + Ms writes

    for (int kt = 0; kt < S_ / 64; ++kt) {
        const int k0 = kt * 64;
        const int buf = kt & 1;
        if (kt + 1 < S_ / 64) stage(buf ^ 1, k0 + 64);   // prefetch next tile

        // K A-fragments (shared by both q-groups)
        bf16x8 kf[4][2];
        #pragma unroll
        for (int cb = 0; cb < 4; ++cb) {
            #pragma unroll
            for (int ks = 0; ks < 2; ++ks) {
                const int rk = cb * 16 + lr;
                const int pp = (ks * 4 + lg) ^ (rk & 7);
                kf[cb][ks] = __builtin_bit_cast(bf16x8,
                    *(const float4*)(&Ks[buf][rk * 64 + pp * 8]));
            }
        }
        // mask C-init values: key = cb*16 + lg*4 + j
        f32x4 mv[4];
        #pragma unroll
        for (int cb = 0; cb < 4; ++cb)
            mv[cb] = __builtin_bit_cast(f32x4,
                *(const float4*)&Ms[k0 + cb * 16 + lg * 4]);

        // V B-fragments (shared by both q-groups)
        bf16x8 vf[4][2];
        #pragma unroll
        for (int cb = 0; cb < 4; ++cb) {
            #pragma unroll
            for (int ks2 = 0; ks2 < 2; ++ks2) {
                const int rv = cb * 16 + lr;
                const int pp = (ks2 * 4 + lg) ^ (rv & 7);
                vf[cb][ks2] = __builtin_bit_cast(bf16x8,
                    *(const float4*)(&Vs[buf][rv * 64 + pp * 8]));
            }
        }

        #pragma unroll
        for (int g = 0; g < 2; ++g) {
            // ---- QK^T swapped, C initialized with mask ----
            f32x4 s[4];
            #pragma unroll
            for (int cb = 0; cb < 4; ++cb) s[cb] = mv[cb];
            __builtin_amdgcn_s_setprio(1);
            #pragma unroll
            for (int cb = 0; cb < 4; ++cb)
                #pragma unroll
                for (int ks = 0; ks < 2; ++ks)
                    s[cb] = __builtin_amdgcn_mfma_f32_16x16x32_bf16(
                        kf[cb][ks], qf[g][ks], s[cb], 0, 0, 0);
            __builtin_amdgcn_s_setprio(0);

            // ---- p = 2^s, convert to bf16 ----
            ushort4 pw[4];
            #pragma unroll
            for (int cb = 0; cb < 4; ++cb) {
                pw[cb].x = f2bf(exp2f(s[cb][0]));
                pw[cb].y = f2bf(exp2f(s[cb][1]));
                pw[cb].z = f2bf(exp2f(s[cb][2]));
                pw[cb].w = f2bf(exp2f(s[cb][3]));
            }
            // ---- P write: P[q=lr][key=cb*16+lg*4+{0..3}] ----
            #pragma unroll
            for (int cb = 0; cb < 4; ++cb)
                *(ushort4*)&Ps[wave][lr * 88 + cb * 16 + lg * 4] = pw[cb];

            // ---- PV + l-sum ----
            bf16x8 pf[2];
            #pragma unroll
            for (int ks2 = 0; ks2 < 2; ++ks2)
                pf[ks2] = __builtin_bit_cast(bf16x8,
                    *(const float4*)(&Ps[wave][lr * 88 + ks2 * 32 + lg * 8]));
            __builtin_amdgcn_s_setprio(1);
            #pragma unroll
            for (int ks2 = 0; ks2 < 2; ++ks2) {
                #pragma unroll
                for (int cb = 0; cb < 4; ++cb)
                    acc[g][cb] = __builtin_amdgcn_mfma_f32_16x16x32_bf16(
                        pf[ks2], vf[cb][ks2], acc[g][cb], 0, 0, 0);
                accl[g] = __builtin_amdgcn_mfma_f32_16x16x32_bf16(
                    pf[ks2], ones, accl[g], 0, 0, 0);
            }
            __builtin_amdgcn_s_setprio(0);
        }

        __syncthreads();   // drains prefetch DMA; swap buffers
    }

    // ---- epilogue: rows q = lg*4+j (acc and accl agree), col hd = cb*16+lr
    #pragma unroll
    for (int g = 0; g < 2; ++g) {
        f32x4 inv;
        #pragma unroll
        for (int j = 0; j < 4; ++j) inv[j] = 1.f / accl[g][j];
        #pragma unroll
        for (int cb = 0; cb < 4; ++cb) {
            #pragma unroll
            for (int j = 0; j < 4; ++j) {
                const size_t row = (size_t)b * S_ + q0 + wave * 32 + g * 16 + lg * 4 + j;
                out[row * D_ + h * HD_ + cb * 16 + lr] = f2bf(acc[g][cb][j] * inv[j]);
            }
        }
    }
}

// ---------------------------------------------------------------------------
extern "C" void kernel_launch(void* const* d_in, const int* in_sizes, int n_in,
                              void* d_out, int out_size, void* d_ws, size_t ws_size,
                              hipStream_t stream)
{
    const float* x    = (const float*)d_in[0];
    const float* mask = (const float*)d_in[1];
    const float* Wq   = (const float*)d_in[2];
    const float* bq   = (const float*)d_in[3];
    const float* Wk   = (const float*)d_in[4];
    const float* bk   = (const float*)d_in[5];
    const float* Wv   = (const float*)d_in[6];
    const float* bv   = (const float*)d_in[7];
    const float* Wo   = (const float*)d_in[8];
    const float* bo   = (const float*)d_in[9];
    float* out = (float*)d_out;

    const size_t NE = (size_t)B_ * S_ * D_;  // 6291456
    ushortT* xb  = (ushortT*)d_ws;
    ushortT* qb  = xb + NE;
    ushortT* kb  = qb + NE;
    ushortT* vb  = kb + NE;
    ushortT* vtb = vb + NE;
    ushortT* ab  = vtb + NE;
    ushortT* wt4 = ab + NE;                  // 4 * 768 * 768

    convert_f32_bf16<<<NE / 2048, 256, 0, stream>>>(x, xb);
    transpose_w<<<dim3(12, 12, 4), 256, 0, stream>>>(Wq, Wk, Wv, Wo, wt4);

    qkv_gemm<<<dim3(M_ / 128, 12, 3), 256, 0, stream>>>(
        xb, wt4, bq, bk, bv, qb, kb, vb);

    transpose_v<<<dim3(S_ / 64, H_, B_), 256, 0, stream>>>(vb, vtb);

    attn_mfma<<<768, 256, 0, stream>>>(qb, kb, vtb, mask, ab);

    o_gemm<<<dim3(M_ / 128, 12), 256, 0, stream>>>(
        ab, wt4 + 3 * 768 * 768, bo, out);
}

// Round 6
// 187.172 us; speedup vs baseline: 13.3462x; 1.0014x over previous
//
#include <hip/hip_runtime.h>
#include <cmath>

#define B_ 4
#define S_ 2048
#define D_ 768
#define H_ 12
#define HD_ 64
#define SCALE_ 0.125f
#define LOG2E_ 1.4426950408889634f
#define M_ 8192

typedef unsigned short ushortT;
typedef __attribute__((ext_vector_type(8))) __bf16 bf16x8;
typedef __attribute__((ext_vector_type(4))) __bf16 bf16x4;
typedef __attribute__((ext_vector_type(4))) float f32x4;
typedef __attribute__((ext_vector_type(4))) short s16x4;

typedef __attribute__((address_space(1))) const void glb_cv;
typedef __attribute__((address_space(3))) void lds_v;

__device__ inline ushortT f2bf(float f) {
    return __builtin_bit_cast(ushortT, (__bf16)f);
}

__device__ inline void gload_lds16(const void* g, void* l) {
    __builtin_amdgcn_global_load_lds((glb_cv*)g, (lds_v*)l, 16, 0, 0);
}

// 16x16x16 bf16 MFMA (K=16): B-fragment layout (k = 4*lg + i) matches the
// C/D row layout of a 16x16 MFMA — lets QK^T output feed PV with no LDS.
__device__ inline f32x4 mfma16(bf16x4 a, bf16x4 b, f32x4 c) {
#if __has_builtin(__builtin_amdgcn_mfma_f32_16x16x16_bf16)
    return __builtin_amdgcn_mfma_f32_16x16x16_bf16(a, b, c, 0, 0, 0);
#elif __has_builtin(__builtin_amdgcn_mfma_f32_16x16x16bf16_1k)
    return __builtin_amdgcn_mfma_f32_16x16x16bf16_1k(
        __builtin_bit_cast(s16x4, a), __builtin_bit_cast(s16x4, b), c, 0, 0, 0);
#else
    asm("v_mfma_f32_16x16x16_bf16 %0, %1, %2, %0" : "+v"(c) : "v"(a), "v"(b));
    return c;
#endif
}

// ---------------------------------------------------------------------------
// convert x fp32 -> bf16, 8 el/thread
// ---------------------------------------------------------------------------
__global__ __launch_bounds__(256)
void convert_f32_bf16(const float* __restrict__ in, ushortT* __restrict__ out)
{
    const size_t i = ((size_t)blockIdx.x * 256 + threadIdx.x) * 8;
    float4 a = *(const float4*)(in + i);
    float4 b = *(const float4*)(in + i + 4);
    union { ushortT u[8]; float4 f; } o;
    o.u[0] = f2bf(a.x); o.u[1] = f2bf(a.y); o.u[2] = f2bf(a.z); o.u[3] = f2bf(a.w);
    o.u[4] = f2bf(b.x); o.u[5] = f2bf(b.y); o.u[6] = f2bf(b.z); o.u[7] = f2bf(b.w);
    *(float4*)(out + i) = o.f;
}

// ---------------------------------------------------------------------------
// transpose+convert W [768,768] f32 -> Wt bf16 (Wt[n][k] = W[k][n]).
// ---------------------------------------------------------------------------
__global__ __launch_bounds__(256)
void transpose_w(const float* __restrict__ W0, const float* __restrict__ W1,
                 const float* __restrict__ W2, const float* __restrict__ W3,
                 ushortT* __restrict__ wt4)
{
    const float* W = (blockIdx.z == 0) ? W0 : (blockIdx.z == 1) ? W1
                   : (blockIdx.z == 2) ? W2 : W3;
    ushortT* o = wt4 + (size_t)blockIdx.z * 768 * 768;
    __shared__ float T[64][65];
    const int tid = threadIdx.x;
    const int k0 = blockIdx.x * 64, n0 = blockIdx.y * 64;

    for (int t = tid; t < 1024; t += 256) {
        const int r = t >> 4, c4 = (t & 15) << 2;
        float4 v = *(const float4*)&W[(size_t)(k0 + r) * 768 + n0 + c4];
        T[r][c4 + 0] = v.x; T[r][c4 + 1] = v.y;
        T[r][c4 + 2] = v.z; T[r][c4 + 3] = v.w;
    }
    __syncthreads();
    for (int t = tid; t < 1024; t += 256) {
        const int r = t >> 4, c4 = (t & 15) << 2;
        union { ushortT u[4]; unsigned long long v; } ov;
        ov.u[0] = f2bf(T[c4 + 0][r]); ov.u[1] = f2bf(T[c4 + 1][r]);
        ov.u[2] = f2bf(T[c4 + 2][r]); ov.u[3] = f2bf(T[c4 + 3][r]);
        *(unsigned long long*)&o[(size_t)(n0 + r) * 768 + k0 + c4] = ov.v;
    }
}

// ---------------------------------------------------------------------------
// MFMA GEMM core: C[128x64] = A[m0..,768] * Bt[n0..,768]^T  (bf16, fp32 acc)
// ---------------------------------------------------------------------------
__device__ inline void gemm_core_128x64(
    const ushortT* __restrict__ A, const ushortT* __restrict__ Bt,
    ushortT* As, ushortT* Bs, int m0, int n0, f32x4 acc[4][2])
{
    const int tid  = threadIdx.x;
    const int lane = tid & 63;
    const int wave = tid >> 6;
    const int lr = lane & 15, lg = lane >> 4;
    const int wr = wave >> 1, wc = wave & 1;

    #pragma unroll
    for (int mi = 0; mi < 4; ++mi)
        #pragma unroll
        for (int ni = 0; ni < 2; ++ni)
            acc[mi][ni] = (f32x4){0.f, 0.f, 0.f, 0.f};

    #pragma unroll 1
    for (int k0 = 0; k0 < 768; k0 += 64) {
        __syncthreads();
        #pragma unroll
        for (int it = 0; it < 4; ++it) {
            const int ci = it * 256 + tid;
            const int row = ci >> 3, c = ci & 7;
            const int sc = c ^ (row & 7);
            gload_lds16(A + (size_t)(m0 + row) * 768 + k0 + sc * 8,
                        As + (size_t)(it * 256 + wave * 64) * 8);
        }
        #pragma unroll
        for (int it = 0; it < 2; ++it) {
            const int ci = it * 256 + tid;
            const int row = ci >> 3, c = ci & 7;
            const int sc = c ^ (row & 7);
            gload_lds16(Bt + (size_t)(n0 + row) * 768 + k0 + sc * 8,
                        Bs + (size_t)(it * 256 + wave * 64) * 8);
        }
        __syncthreads();

        #pragma unroll
        for (int ks = 0; ks < 2; ++ks) {
            bf16x8 af[4], bfr[2];
            #pragma unroll
            for (int mi = 0; mi < 4; ++mi) {
                const int row = wr * 64 + mi * 16 + lr;
                const int ch = (ks * 4 + lg) ^ (row & 7);
                af[mi] = __builtin_bit_cast(bf16x8, *(const float4*)(As + row * 64 + ch * 8));
            }
            #pragma unroll
            for (int ni = 0; ni < 2; ++ni) {
                const int row = wc * 32 + ni * 16 + lr;
                const int ch = (ks * 4 + lg) ^ (row & 7);
                bfr[ni] = __builtin_bit_cast(bf16x8, *(const float4*)(Bs + row * 64 + ch * 8));
            }
            #pragma unroll
            for (int mi = 0; mi < 4; ++mi)
                #pragma unroll
                for (int ni = 0; ni < 2; ++ni)
                    acc[mi][ni] = __builtin_amdgcn_mfma_f32_16x16x32_bf16(
                        af[mi], bfr[ni], acc[mi][ni], 0, 0, 0);
        }
    }
}

// ---------------------------------------------------------------------------
// QKV fused GEMM: z in {Q,K,V}. Q/K -> bf16 split-head [B,H,S,HD] (Q scaled
// by SCALE*log2e); V -> written DIRECTLY transposed as Vt [B,H,HD,S].
// ---------------------------------------------------------------------------
__global__ __launch_bounds__(256)
void qkv_gemm(const ushortT* __restrict__ xb, const ushortT* __restrict__ wt4,
              const float* __restrict__ bq, const float* __restrict__ bk,
              const float* __restrict__ bv,
              ushortT* __restrict__ qb, ushortT* __restrict__ kb,
              ushortT* __restrict__ vtb)
{
    __shared__ __align__(16) ushortT As[128 * 64];
    __shared__ __align__(16) ushortT Bs[64 * 64];
    const int z = blockIdx.z;
    const ushortT* Wt = wt4 + (size_t)z * 768 * 768;
    const float* bias = (z == 0) ? bq : (z == 1) ? bk : bv;
    const float scale = (z == 0) ? (SCALE_ * LOG2E_) : 1.0f;

    const int m0 = blockIdx.x * 128, n0 = blockIdx.y * 64;
    f32x4 acc[4][2];
    gemm_core_128x64(xb, Wt, As, Bs, m0, n0, acc);

    const int tid = threadIdx.x;
    const int lane = tid & 63, wave = tid >> 6;
    const int lr = lane & 15, lg = lane >> 4;
    const int wr = wave >> 1, wc = wave & 1;
    const int h = n0 >> 6;

    if (z == 2) {
        // V: write transposed Vt[b][h][hd=nn][s]; j runs along s -> 8B stores
        #pragma unroll
        for (int ni = 0; ni < 2; ++ni) {
            const int nn = wc * 32 + ni * 16 + lr;
            const float bb = bias[n0 + nn];
            #pragma unroll
            for (int mi = 0; mi < 4; ++mi) {
                const int mb = m0 + wr * 64 + mi * 16 + lg * 4;
                const int b = mb >> 11, s = mb & 2047;
                ushort4 ov;
                ov.x = f2bf(acc[mi][ni][0] + bb);
                ov.y = f2bf(acc[mi][ni][1] + bb);
                ov.z = f2bf(acc[mi][ni][2] + bb);
                ov.w = f2bf(acc[mi][ni][3] + bb);
                *(ushort4*)&vtb[(((size_t)b * H_ + h) * HD_ + nn) * S_ + s] = ov;
            }
        }
    } else {
        ushortT* out = (z == 0) ? qb : kb;
        #pragma unroll
        for (int ni = 0; ni < 2; ++ni) {
            const int nn = wc * 32 + ni * 16 + lr;
            const float bb = bias[n0 + nn];
            #pragma unroll
            for (int mi = 0; mi < 4; ++mi) {
                #pragma unroll
                for (int j = 0; j < 4; ++j) {
                    const int m = m0 + wr * 64 + mi * 16 + lg * 4 + j;
                    const int b = m >> 11, s = m & 2047;
                    out[(((size_t)b * H_ + h) * S_ + s) * HD_ + nn] =
                        f2bf((acc[mi][ni][j] + bb) * scale);
                }
            }
        }
    }
}

// ---------------------------------------------------------------------------
// Output projection: ab bf16 [M,768] x Wo^T -> fp32 [M,768] + bias.
// ---------------------------------------------------------------------------
__global__ __launch_bounds__(256)
void o_gemm(const ushortT* __restrict__ ab, const ushortT* __restrict__ wto,
            const float* __restrict__ bo, float* __restrict__ out)
{
    __shared__ __align__(16) ushortT As[128 * 64];
    __shared__ __align__(16) ushortT Bs[64 * 64];
    const int m0 = blockIdx.x * 128, n0 = blockIdx.y * 64;
    f32x4 acc[4][2];
    gemm_core_128x64(ab, wto, As, Bs, m0, n0, acc);

    const int tid = threadIdx.x;
    const int lane = tid & 63, wave = tid >> 6;
    const int lr = lane & 15, lg = lane >> 4;
    const int wr = wave >> 1, wc = wave & 1;

    #pragma unroll
    for (int ni = 0; ni < 2; ++ni) {
        const int n = n0 + wc * 32 + ni * 16 + lr;
        const float bb = bo[n];
        #pragma unroll
        for (int mi = 0; mi < 4; ++mi) {
            #pragma unroll
            for (int j = 0; j < 4; ++j) {
                const int m = m0 + wr * 64 + mi * 16 + lg * 4 + j;
                out[(size_t)m * 768 + n] = acc[mi][ni][j] + bb;
            }
        }
    }
}

// ---------------------------------------------------------------------------
// Flash attention: swapped QK^T (16x16x32), fixed-max exp2 softmax, and PV
// via 16x16x16 MFMA whose B-fragment layout equals QK^T's C-layout -> P stays
// entirely in registers (no LDS roundtrip). l-sum via ones-MFMA (no shuffles).
// Block = 128 thr = 2 waves; 64 q/wave (4 groups of 16), 128 q/block.
// KV tiles of 64, double-buffered via global_load_lds (pre-swizzled source).
// Grid: 768 blocks, XCD-clustered.
// ---------------------------------------------------------------------------
__global__ __launch_bounds__(128, 2)
void attn_mfma(const ushortT* __restrict__ Q, const ushortT* __restrict__ K,
               const ushortT* __restrict__ Vt, const float* __restrict__ mask,
               ushortT* __restrict__ out)
{
    __shared__ __align__(16) ushortT Ks[2][64 * 64];
    __shared__ __align__(16) ushortT Vs[2][64 * 64];
    __shared__ float Ms[S_];

    const int tid  = threadIdx.x;
    const int lane = tid & 63;
    const int wave = tid >> 6;           // 0..1
    const int lr   = lane & 15;
    const int lg   = lane >> 4;

    // XCD-clustered decode: 8 XCDs x 6 bh x 16 q-blocks of 128
    const int gid  = blockIdx.x;
    const int xcd  = gid & 7;
    const int w    = gid >> 3;           // 0..95
    const int bh_i = xcd * 6 + (w >> 4); // 0..47
    const int q0   = (w & 15) * 128;
    const int b    = bh_i / H_;
    const int h    = bh_i % H_;
    const size_t bh = (size_t)bh_i;

    // stage mask row, scaled to exp2 domain
    for (int f = tid; f < 512; f += 128) {
        float4 mv = *(const float4*)&mask[(size_t)b * S_ + f * 4];
        mv.x *= LOG2E_; mv.y *= LOG2E_; mv.z *= LOG2E_; mv.w *= LOG2E_;
        *(float4*)&Ms[f * 4] = mv;
    }

    // Q B-fragments: 4 groups of 16 q-rows (col = q = lr)
    bf16x8 qf[4][2];
    #pragma unroll
    for (int g = 0; g < 4; ++g) {
        const ushortT* Qg = Q + (bh * S_ + q0 + wave * 64 + g * 16 + lr) * HD_;
        qf[g][0] = __builtin_bit_cast(bf16x8, *(const float4*)(Qg + lg * 8));
        qf[g][1] = __builtin_bit_cast(bf16x8, *(const float4*)(Qg + 32 + lg * 8));
    }

    const ushortT* Kg = K  + bh * S_ * HD_;
    const ushortT* Vg = Vt + bh * HD_ * S_;

    bf16x4 onesA;
    #pragma unroll
    for (int i = 0; i < 4; ++i) onesA[i] = (__bf16)1.0f;

    f32x4 acc[4][4];     // [group][hd-block]: lane q = lr, hd = cbh*16+4lg+j
    f32x4 accl[4];       // l-sum per group (all regs equal, q = lr)
    #pragma unroll
    for (int g = 0; g < 4; ++g) {
        #pragma unroll
        for (int cb = 0; cb < 4; ++cb) acc[g][cb] = (f32x4){0.f, 0.f, 0.f, 0.f};
        accl[g] = (f32x4){0.f, 0.f, 0.f, 0.f};
    }

    auto stage = [&](int bsel, int k0) {
        #pragma unroll
        for (int it = 0; it < 4; ++it) {
            const int ci = it * 128 + tid;
            const int row = ci >> 3, c = ci & 7, sc = c ^ (row & 7);
            gload_lds16(Kg + (size_t)(k0 + row) * HD_ + sc * 8,
                        &Ks[bsel][(it * 128 + wave * 64) * 8]);
        }
        #pragma unroll
        for (int it = 0; it < 4; ++it) {
            const int ci = it * 128 + tid;
            const int row = ci >> 3, c = ci & 7, sc = c ^ (row & 7);
            gload_lds16(Vg + (size_t)row * S_ + k0 + sc * 8,
                        &Vs[bsel][(it * 128 + wave * 64) * 8]);
        }
    };

    stage(0, 0);
    __syncthreads();   // drains stage DMA + Ms writes

    for (int kt = 0; kt < S_ / 64; ++kt) {
        const int k0 = kt * 64;
        const int buf = kt & 1;
        if (kt + 1 < S_ / 64) stage(buf ^ 1, k0 + 64);   // prefetch next tile

        // K A-fragments (shared by all q-groups)
        bf16x8 kf[4][2];
        #pragma unroll
        for (int cb = 0; cb < 4; ++cb) {
            #pragma unroll
            for (int ks = 0; ks < 2; ++ks) {
                const int rk = cb * 16 + lr;
                const int pp = (ks * 4 + lg) ^ (rk & 7);
                kf[cb][ks] = __builtin_bit_cast(bf16x8,
                    *(const float4*)(&Ks[buf][rk * 64 + pp * 8]));
            }
        }
        // mask C-init: key = cb*16 + 4lg + j
        f32x4 mv[4];
        #pragma unroll
        for (int cb = 0; cb < 4; ++cb)
            mv[cb] = __builtin_bit_cast(f32x4,
                *(const float4*)&Ms[k0 + cb * 16 + lg * 4]);

        // V A-fragments for PV-16: A[hd=cbh*16+lr][key=slice*16+4lg+i], 8B each
        bf16x4 vf[4][4];
        #pragma unroll
        for (int cbh = 0; cbh < 4; ++cbh) {
            const int rv = cbh * 16 + lr;
            #pragma unroll
            for (int sl = 0; sl < 4; ++sl) {
                const int cg = sl * 2 + (lg >> 1);
                const int cl = cg ^ (rv & 7);
                vf[cbh][sl] = __builtin_bit_cast(bf16x4,
                    *(const ulonglong1*)(&Vs[buf][rv * 64 + cl * 8 + (lg & 1) * 4]));
            }
        }

        #pragma unroll
        for (int g = 0; g < 4; ++g) {
            // ---- QK^T swapped, C initialized with mask ----
            f32x4 s[4];
            __builtin_amdgcn_s_setprio(1);
            #pragma unroll
            for (int cb = 0; cb < 4; ++cb) {
                s[cb] = __builtin_amdgcn_mfma_f32_16x16x32_bf16(
                    kf[cb][0], qf[g][0], mv[cb], 0, 0, 0);
                s[cb] = __builtin_amdgcn_mfma_f32_16x16x32_bf16(
                    kf[cb][1], qf[g][1], s[cb], 0, 0, 0);
            }
            __builtin_amdgcn_s_setprio(0);

            // ---- p = 2^s -> bf16x4 (stays in registers: B-frag of PV-16) --
            bf16x4 pb[4];
            #pragma unroll
            for (int cb = 0; cb < 4; ++cb) {
                pb[cb][0] = (__bf16)exp2f(s[cb][0]);
                pb[cb][1] = (__bf16)exp2f(s[cb][1]);
                pb[cb][2] = (__bf16)exp2f(s[cb][2]);
                pb[cb][3] = (__bf16)exp2f(s[cb][3]);
            }

            // ---- PV: O^T[hd][q] += Vt[hd][k] P^T[k][q], plus ones l-sum ----
            __builtin_amdgcn_s_setprio(1);
            #pragma unroll
            for (int sl = 0; sl < 4; ++sl) {
                #pragma unroll
                for (int cbh = 0; cbh < 4; ++cbh)
                    acc[g][cbh] = mfma16(vf[cbh][sl], pb[sl], acc[g][cbh]);
                accl[g] = mfma16(onesA, pb[sl], accl[g]);
            }
            __builtin_amdgcn_s_setprio(0);
        }

        __syncthreads();   // drains prefetch DMA; swap buffers
    }

    // hazard guard for inline-asm MFMA fallback path (VALU read of MFMA dest)
    asm volatile("s_nop 7\n\ts_nop 7" ::: );

    // ---- epilogue: lane q = lr; hd = cbh*16 + 4lg + j (4 consecutive) ----
    #pragma unroll
    for (int g = 0; g < 4; ++g) {
        const float inv = 1.f / accl[g][0];
        const size_t row = (size_t)b * S_ + q0 + wave * 64 + g * 16 + lr;
        #pragma unroll
        for (int cbh = 0; cbh < 4; ++cbh) {
            ushort4 ov;
            ov.x = f2bf(acc[g][cbh][0] * inv);
            ov.y = f2bf(acc[g][cbh][1] * inv);
            ov.z = f2bf(acc[g][cbh][2] * inv);
            ov.w = f2bf(acc[g][cbh][3] * inv);
            *(ushort4*)&out[row * D_ + h * HD_ + cbh * 16 + lg * 4] = ov;
        }
    }
}

// ---------------------------------------------------------------------------
extern "C" void kernel_launch(void* const* d_in, const int* in_sizes, int n_in,
                              void* d_out, int out_size, void* d_ws, size_t ws_size,
                              hipStream_t stream)
{
    const float* x    = (const float*)d_in[0];
    const float* mask = (const float*)d_in[1];
    const float* Wq   = (const float*)d_in[2];
    const float* bq   = (const float*)d_in[3];
    const float* Wk   = (const float*)d_in[4];
    const float* bk   = (const float*)d_in[5];
    const float* Wv   = (const float*)d_in[6];
    const float* bv   = (const float*)d_in[7];
    const float* Wo   = (const float*)d_in[8];
    const float* bo   = (const float*)d_in[9];
    float* out = (float*)d_out;

    const size_t NE = (size_t)B_ * S_ * D_;  // 6291456
    ushortT* xb  = (ushortT*)d_ws;
    ushortT* qb  = xb + NE;
    ushortT* kb  = qb + NE;
    ushortT* vtb = kb + NE;
    ushortT* ab  = vtb + NE;
    ushortT* wt4 = ab + NE;                  // 4 * 768 * 768

    convert_f32_bf16<<<NE / 2048, 256, 0, stream>>>(x, xb);
    transpose_w<<<dim3(12, 12, 4), 256, 0, stream>>>(Wq, Wk, Wv, Wo, wt4);

    qkv_gemm<<<dim3(M_ / 128, 12, 3), 256, 0, stream>>>(
        xb, wt4, bq, bk, bv, qb, kb, vtb);

    attn_mfma<<<768, 128, 0, stream>>>(qb, kb, vtb, mask, ab);

    o_gemm<<<dim3(M_ / 128, 12), 256, 0, stream>>>(
        ab, wt4 + 3 * 768 * 768, bo, out);
}